// Round 2
// baseline (5238.771 us; speedup 1.0000x reference)
//
#include <hip/hip_runtime.h>
#include <cstdint>
#include <cstddef>

#define DEVFN __device__ __forceinline__

// Problem constants
constexpr int B_ = 64, T_ = 197, DIM_ = 768, H_ = 12, HD_ = 64, MLP_ = 3072;
constexpr int N_ = B_ * T_;          // 12608 tokens
constexpr int NE_ = 99;              // even (src) tokens
constexpr int NO_ = 98;              // odd (dst) tokens
constexpr int REFF_ = 16;
constexpr int TM_ = (NE_ - REFF_) + NO_;  // 181 merged tokens
constexpr int NM_ = B_ * TM_;        // 11584 merged rows
constexpr int CHUNK0_ = 6144;        // MLP row-chunk (96 tiles); chunk1 = 5440

// workspace layout (float offsets) — liveness-overlaid, peak ~159 MB
constexpr size_t SZ_QKV = (size_t)N_ * 3 * DIM_;   // 29,048,832
constexpr size_t SZ_H   = (size_t)N_ * DIM_;       //  9,682,944
constexpr size_t SZ_MET = (size_t)N_ * HD_;        //    806,912
constexpr size_t SZ_XM  = (size_t)NM_ * DIM_;      //  8,896,512
constexpr size_t SZ_G   = (size_t)CHUNK0_ * MLP_;  // 18,874,368

constexpr size_t OFF_H   = 0;                       // live: LN1 -> metric GEMM
constexpr size_t OFF_O   = 0;                       // overlay h (dead after metric GEMM)
constexpr size_t OFF_QKV = SZ_H;                    // 9,682,944; live: qkv GEMM -> attn
constexpr size_t OFF_X1  = OFF_QKV;                 // overlay qkv (dead after attn)
constexpr size_t OFF_XM  = OFF_X1 + SZ_H;           // 19,365,888; live: merge -> end
constexpr size_t OFF_H2  = OFF_XM + SZ_XM;          // 28,262,400; live: LN2 -> fc1
constexpr size_t OFF_MET = OFF_QKV + SZ_QKV;        // 38,731,776
constexpr size_t OFF_ROUTE = OFF_MET + SZ_MET;      // ints, 18 per merged row
constexpr size_t SZ_ROUTE  = (size_t)B_ * TM_ * 18; // 208,512
constexpr size_t OFF_NSZ = OFF_ROUTE + SZ_ROUTE;
constexpr size_t OFF_WKM = OFF_NSZ + (size_t)NM_;
constexpr size_t OFF_G   = 0;  // overlay h/o + x1 head (both dead by fc1); ends 18.87M < OFF_XM
// total end: OFF_WKM + 64*768 = 39,807,936 floats = 159.2 MB

// ---------------- reductions ----------------
DEVFN float wave_sum(float v) {
#pragma unroll
  for (int o = 32; o; o >>= 1) v += __shfl_down(v, o, 64);
  return v;
}

DEVFN float block_sum(float v, float* red) {
  v = wave_sum(v);
  int lane = threadIdx.x & 63, wid = threadIdx.x >> 6;
  __syncthreads();
  if (lane == 0) red[wid] = v;
  __syncthreads();
  return red[0] + red[1] + red[2] + red[3];
}

// ---------------- LayerNorm (one block per row, 768 cols) ----------------
__global__ __launch_bounds__(256) void ln_kernel(
    const float* __restrict__ x, const float* __restrict__ g,
    const float* __restrict__ bb, float* __restrict__ out) {
  __shared__ float red[4];
  size_t row = blockIdx.x;
  const float* xr = x + row * DIM_;
  int tid = threadIdx.x;
  float s = 0.f;
  for (int i = tid; i < DIM_; i += 256) s += xr[i];
  s = block_sum(s, red);
  float mean = s * (1.0f / DIM_);
  float vs = 0.f;
  for (int i = tid; i < DIM_; i += 256) { float d = xr[i] - mean; vs = fmaf(d, d, vs); }
  vs = block_sum(vs, red);
  float rstd = rsqrtf(vs * (1.0f / DIM_) + 1e-5f);
  for (int i = tid; i < DIM_; i += 256)
    out[row * DIM_ + i] = (xr[i] - mean) * rstd * g[i] + bb[i];
}

// ---------------- head-averaged K weights: wkm[d][c] = mean_h w_qkv[768+h*64+d][c] ----------------
__global__ __launch_bounds__(256) void wkmean_kernel(const float* __restrict__ wqkv,
                                                     float* __restrict__ wkm) {
  int idx = blockIdx.x * 256 + threadIdx.x;
  if (idx >= HD_ * DIM_) return;
  int d = idx / DIM_, c = idx % DIM_;
  float s = 0.f;
  for (int h2 = 0; h2 < H_; h2++) s += wqkv[(size_t)(DIM_ + h2 * HD_ + d) * DIM_ + c];
  wkm[idx] = s * (1.0f / H_);
}

// ---------------- generic fp32 GEMM: C = act(A @ B^T + bias) (+ res) ----------------
// A: [M,K] row-major, Bm: [Nn,K] row-major.  M%64==0, Nn%64==0, K%16==0 assumed.
__global__ __launch_bounds__(256) void gemm_bt(
    const float* __restrict__ A, const float* __restrict__ Bm,
    const float* __restrict__ bias, const float* __restrict__ res,
    float* __restrict__ C, int M, int Nn, int K, int act) {
  __shared__ float As[16][65];
  __shared__ float Bs[16][65];
  const int tid = threadIdx.x;
  const int tx = tid & 15, ty = tid >> 4;
  const int m0 = blockIdx.y * 64, n0 = blockIdx.x * 64;
  float acc[4][4] = {};
  for (int k0 = 0; k0 < K; k0 += 16) {
#pragma unroll
    for (int l = 0; l < 4; ++l) {
      int idx = tid + l * 256;
      int mm = idx >> 4, kk = idx & 15;
      As[kk][mm] = A[(size_t)(m0 + mm) * K + (k0 + kk)];
      Bs[kk][mm] = Bm[(size_t)(n0 + mm) * K + (k0 + kk)];
    }
    __syncthreads();
#pragma unroll
    for (int kk = 0; kk < 16; ++kk) {
      float av[4], bv[4];
#pragma unroll
      for (int i = 0; i < 4; i++) av[i] = As[kk][ty * 4 + i];
#pragma unroll
      for (int j = 0; j < 4; j++) bv[j] = Bs[kk][tx * 4 + j];
#pragma unroll
      for (int i = 0; i < 4; i++)
#pragma unroll
        for (int j = 0; j < 4; j++) acc[i][j] = fmaf(av[i], bv[j], acc[i][j]);
    }
    __syncthreads();
  }
#pragma unroll
  for (int i = 0; i < 4; i++) {
    int mm = m0 + ty * 4 + i;
    size_t base = (size_t)mm * Nn + n0 + tx * 4;
    float4 v;
    float* vv = &v.x;
#pragma unroll
    for (int j = 0; j < 4; j++) {
      float t = acc[i][j];
      int nn = n0 + tx * 4 + j;
      if (bias) t += bias[nn];
      if (act) t = 0.5f * t * (1.0f + erff(t * 0.70710678118654752440f));
      if (res) t += res[base + j];
      vv[j] = t;
    }
    *reinterpret_cast<float4*>(C + base) = v;
  }
}

// ---------------- attention: one block per (b, h, query-chunk of 32) ----------------
__global__ __launch_bounds__(256) void attn_kernel(
    const float* __restrict__ qkv, const float* __restrict__ asize,
    float* __restrict__ o) {
  constexpr int TQ = 32;
  __shared__ float S[TQ][197];
  __shared__ float qs[TQ][65];
  __shared__ float lb[197];
  int blk = blockIdx.x;
  int c = blk % 7;
  int bh = blk / 7;
  int h = bh % H_;
  int b = bh / H_;
  int i0 = c * TQ;
  int nr = min(TQ, T_ - i0);
  int tid = threadIdx.x;
  for (int j = tid; j < T_; j += 256) lb[j] = logf(asize[(size_t)b * T_ + j]);
  for (int idx = tid; idx < nr * 64; idx += 256) {
    int ii = idx >> 6, d = idx & 63;
    qs[ii][d] = qkv[((size_t)(b * T_) + i0 + ii) * (3 * DIM_) + h * HD_ + d];
  }
  __syncthreads();
  for (int idx = tid; idx < nr * T_; idx += 256) {
    int ii = idx / T_, j = idx - ii * T_;
    const float* kr = qkv + ((size_t)(b * T_) + j) * (3 * DIM_) + DIM_ + h * HD_;
    float acc = 0.f;
#pragma unroll
    for (int d = 0; d < 64; d++) acc = fmaf(qs[ii][d], kr[d], acc);
    S[ii][j] = acc * 0.125f + lb[j];
  }
  __syncthreads();
  int lane = tid & 63, wid = tid >> 6;
  for (int ii = wid; ii < nr; ii += 4) {
    float mx = -INFINITY;
    for (int j = lane; j < T_; j += 64) mx = fmaxf(mx, S[ii][j]);
#pragma unroll
    for (int off = 32; off; off >>= 1) mx = fmaxf(mx, __shfl_xor(mx, off, 64));
    float sm = 0.f;
    for (int j = lane; j < T_; j += 64) {
      float e = expf(S[ii][j] - mx);
      S[ii][j] = e;
      sm += e;
    }
#pragma unroll
    for (int off = 32; off; off >>= 1) sm += __shfl_xor(sm, off, 64);
    float inv = 1.0f / sm;
    for (int j = lane; j < T_; j += 64) S[ii][j] *= inv;
  }
  __syncthreads();
  for (int idx = tid; idx < nr * 64; idx += 256) {
    int ii = idx >> 6, d = idx & 63;
    float acc = 0.f;
    const float* vbase = qkv + (size_t)(b * T_) * (3 * DIM_) + 2 * DIM_ + h * HD_ + d;
    for (int j = 0; j < T_; j++) acc = fmaf(S[ii][j], vbase[(size_t)j * (3 * DIM_)], acc);
    o[((size_t)(b * T_) + i0 + ii) * DIM_ + h * HD_ + d] = acc;
  }
}

// ---------------- ToMe matching: one block per batch ----------------
__global__ __launch_bounds__(256) void match_kernel(
    const float* __restrict__ metric, const float* __restrict__ asize,
    int* __restrict__ route, float* __restrict__ nsz,
    float* __restrict__ out_ns, float* __restrict__ out_rci) {
  __shared__ float m[197][65];
  __shared__ float nmax[99];
  __shared__ int nidx[99];
  __shared__ int rnk[99];
  __shared__ int srcr[16];
  __shared__ int dstr[16];
  __shared__ int unmp[99];
  int b = blockIdx.x;
  int tid = threadIdx.x;
  int lane = tid & 63, wid = tid >> 6;

  // load + L2-normalize metric rows
  if (tid < T_) {
    const float* mr = metric + ((size_t)b * T_ + tid) * HD_;
    float ss = 0.f;
#pragma unroll
    for (int d = 0; d < 64; d++) { float v = mr[d]; ss = fmaf(v, v, ss); }
    float nrm = sqrtf(ss);
#pragma unroll
    for (int d = 0; d < 64; d++) m[tid][d] = mr[d] / nrm;
  }
  __syncthreads();

  // per even-row argmax over 98 odd rows (first-occurrence ties)
  for (int i = wid; i < NE_; i += 4) {
    if (i == 0) {
      if (lane == 0) { nmax[0] = -INFINITY; nidx[0] = 0; }
      continue;
    }
    float bv = -INFINITY;
    int bj = 1 << 30;
    for (int j = lane; j < NO_; j += 64) {
      const float* a = m[2 * i];
      const float* bb = m[2 * j + 1];
      float s = 0.f;
#pragma unroll
      for (int d = 0; d < 64; d++) s = fmaf(a[d], bb[d], s);
      if (s > bv) { bv = s; bj = j; }  // per-lane j ascending -> '>' keeps first
    }
#pragma unroll
    for (int off = 32; off; off >>= 1) {
      float ov = __shfl_down(bv, off, 64);
      int oj = __shfl_down(bj, off, 64);
      if (ov > bv || (ov == bv && oj < bj)) { bv = ov; bj = oj; }
    }
    if (lane == 0) { nmax[i] = bv; nidx[i] = bj; }
  }
  __syncthreads();

  // stable descending rank  (rank = position in argsort(-node_max))
  if (tid < NE_) {
    float v = nmax[tid];
    int r = 0;
    for (int i2 = 0; i2 < NE_; i2++) {
      float v2 = nmax[i2];
      r += (v2 > v) || (v2 == v && i2 < tid);
    }
    rnk[tid] = r;
  }
  __syncthreads();
  if (tid < NE_ && rnk[tid] < REFF_) { srcr[rnk[tid]] = tid; dstr[rnk[tid]] = nidx[tid]; }
  __syncthreads();
  // unmerged rows: ascending-index position; routing row = single token
  if (tid < NE_ && rnk[tid] >= REFF_) {
    int p = 0;
    for (int i2 = 0; i2 < tid; i2++) p += (rnk[i2] >= REFF_);
    unmp[tid] = p;
    int* rr = route + ((size_t)b * TM_ + p) * 18;
    rr[0] = 1;
    rr[1] = 2 * tid;
  }
  // dst rows: base odd token + merged-in src tokens (in r order)
  if (tid < NO_) {
    int d = tid;
    int* rr = route + ((size_t)b * TM_ + (NE_ - REFF_) + d) * 18;
    int cnt = 1;
    rr[1] = 2 * d + 1;
    for (int r = 0; r < REFF_; r++)
      if (dstr[r] == d) { cnt++; rr[cnt] = 2 * srcr[r]; }
    rr[0] = cnt;
  }
  __syncthreads();

  // new_size = merge(attn_size)
  for (int row = tid; row < TM_; row += 256) {
    const int* rr = route + ((size_t)b * TM_ + row) * 18;
    int cnt = rr[0];
    float s = 0.f;
    for (int t2 = 0; t2 < cnt; t2++) s += asize[(size_t)b * T_ + rr[1 + t2]];
    out_ns[(size_t)b * TM_ + row] = s;
    nsz[(size_t)b * TM_ + row] = s;
  }
  // rci: landing-row index (0-based) minus 1, tokens 1..196
  for (int t = 1 + tid; t < T_; t += 256) {
    int val;
    if (t & 1) {
      val = (NE_ - REFF_ - 1) + ((t - 1) >> 1);  // 82 + j
    } else {
      int i = t >> 1;
      val = (rnk[i] >= REFF_) ? (unmp[i] - 1) : ((NE_ - REFF_ - 1) + nidx[i]);
    }
    out_rci[(size_t)b * (T_ - 1) + (t - 1)] = (float)val;
  }
}

// ---------------- merged x = merge(x1 * size) / new_size : one block per merged row ----------------
__global__ __launch_bounds__(256) void merge_x_kernel(
    const float* __restrict__ x1, const float* __restrict__ asize,
    const int* __restrict__ route, const float* __restrict__ nsz,
    float* __restrict__ xm) {
  int row = blockIdx.x;
  int b = row / TM_;
  const int* rr = route + (size_t)row * 18;
  __shared__ int cnt_s;
  __shared__ int toks[17];
  __shared__ float szs[17];
  int tid = threadIdx.x;
  if (tid == 0) cnt_s = rr[0];
  __syncthreads();
  int cnt = cnt_s;
  if (tid < cnt) {
    int t = rr[1 + tid];
    toks[tid] = t;
    szs[tid] = asize[(size_t)b * T_ + t];
  }
  __syncthreads();
  float ns = nsz[row];
  for (int e = tid; e < DIM_; e += 256) {
    float acc = 0.f;
    for (int c2 = 0; c2 < cnt; c2++)
      acc = fmaf(x1[((size_t)b * T_ + toks[c2]) * DIM_ + e], szs[c2], acc);
    xm[(size_t)row * DIM_ + e] = acc / ns;
  }
}

// ---------------- launch ----------------
extern "C" void kernel_launch(void* const* d_in, const int* in_sizes, int n_in,
                              void* d_out, int out_size, void* d_ws, size_t ws_size,
                              hipStream_t stream) {
  const float* x_in = (const float*)d_in[0];
  const float* asize = (const float*)d_in[1];
  const float* ln1g = (const float*)d_in[2];
  const float* ln1b = (const float*)d_in[3];
  const float* wqkv = (const float*)d_in[4];
  const float* wproj = (const float*)d_in[5];
  const float* bproj = (const float*)d_in[6];
  const float* ln2g = (const float*)d_in[7];
  const float* ln2b = (const float*)d_in[8];
  const float* wfc1 = (const float*)d_in[9];
  const float* bfc1 = (const float*)d_in[10];
  const float* wfc2 = (const float*)d_in[11];
  const float* bfc2 = (const float*)d_in[12];

  float* ws = (float*)d_ws;
  float* h = ws + OFF_H;
  float* qkv = ws + OFF_QKV;
  float* o = ws + OFF_O;     // overlays h (dead after metric GEMM)
  float* x1 = ws + OFF_X1;   // overlays qkv (dead after attn)
  float* met = ws + OFF_MET;
  float* xm = ws + OFF_XM;
  float* h2 = ws + OFF_H2;
  int* route = (int*)(ws + OFF_ROUTE);
  float* nsz = ws + OFF_NSZ;
  float* wkm = ws + OFF_WKM;
  float* g = ws + OFF_G;     // overlays h/o + x1 head (dead by fc1)

  float* out_x = (float*)d_out;
  float* out_ns = out_x + (size_t)NM_ * DIM_;
  float* out_rci = out_ns + NM_;

  wkmean_kernel<<<(HD_ * DIM_ + 255) / 256, 256, 0, stream>>>(wqkv, wkm);
  ln_kernel<<<N_, 256, 0, stream>>>(x_in, ln1g, ln1b, h);
  gemm_bt<<<dim3(3 * DIM_ / 64, N_ / 64), 256, 0, stream>>>(
      h, wqkv, nullptr, nullptr, qkv, N_, 3 * DIM_, DIM_, 0);
  gemm_bt<<<dim3(1, N_ / 64), 256, 0, stream>>>(
      h, wkm, nullptr, nullptr, met, N_, HD_, DIM_, 0);
  attn_kernel<<<B_ * H_ * 7, 256, 0, stream>>>(qkv, asize, o);
  gemm_bt<<<dim3(DIM_ / 64, N_ / 64), 256, 0, stream>>>(
      o, wproj, bproj, x_in, x1, N_, DIM_, DIM_, 0);
  match_kernel<<<B_, 256, 0, stream>>>(met, asize, route, nsz, out_ns, out_rci);
  merge_x_kernel<<<NM_, 256, 0, stream>>>(x1, asize, route, nsz, xm);
  ln_kernel<<<NM_, 256, 0, stream>>>(xm, ln2g, ln2b, h2);

  // MLP in 2 row-chunks so the fc1 activation fits the compacted workspace
  int chunk_rows[2] = {CHUNK0_, NM_ - CHUNK0_};
  int r0 = 0;
  for (int c = 0; c < 2; c++) {
    int rows = chunk_rows[c];
    const float* h2c = h2 + (size_t)r0 * DIM_;
    const float* xmc = xm + (size_t)r0 * DIM_;
    float* outc = out_x + (size_t)r0 * DIM_;
    gemm_bt<<<dim3(MLP_ / 64, rows / 64), 256, 0, stream>>>(
        h2c, wfc1, bfc1, nullptr, g, rows, MLP_, DIM_, 1);
    gemm_bt<<<dim3(DIM_ / 64, rows / 64), 256, 0, stream>>>(
        g, wfc2, bfc2, xmc, outc, rows, DIM_, MLP_, 0);
    r0 += rows;
  }
}

// Round 3
// 1283.275 us; speedup vs baseline: 4.0823x; 4.0823x over previous
//
#include <hip/hip_runtime.h>
#include <cstdint>
#include <cstddef>

#define DEVFN __device__ __forceinline__

typedef __attribute__((ext_vector_type(8))) short short8;
typedef __attribute__((ext_vector_type(4))) float f32x4;

// Problem constants
constexpr int B_ = 64, T_ = 197, DIM_ = 768, H_ = 12, HD_ = 64, MLP_ = 3072;
constexpr int N_ = B_ * T_;          // 12608 tokens
constexpr int NE_ = 99, NO_ = 98, REFF_ = 16;
constexpr int TM_ = (NE_ - REFF_) + NO_;  // 181 merged tokens
constexpr int NM_ = B_ * TM_;        // 11584 merged rows
constexpr int MCH_ = 5792;           // MLP row chunk (2 chunks)

// ---------------- workspace layout (BYTE offsets; all 16B-aligned) ----------------
// Region A [0, 58,097,664): h fp32 -> qkv_b bf16 -> x1 fp32 -> (h2b bf16 + gbc bf16)
// Region B [58,097,664, 77,463,552): hb bf16 -> ob bf16
// Region C [77,463,552, 113,049,600): xm fp32
// Region D [113,049,600, 116,277,248): met fp32
// Region E: wkm, route, nsz, bf16 weights.  Total = 131,510,016 B (< 159 MB proven safe)
constexpr size_t BOFF_A    = 0;
constexpr size_t BOFF_GBC  = 17793024;   // inside A, after h2b
constexpr size_t BOFF_B    = 58097664;
constexpr size_t BOFF_C    = 77463552;
constexpr size_t BOFF_D    = 113049600;
constexpr size_t BOFF_WKM  = 116277248;
constexpr size_t BOFF_RT   = 116473856;
constexpr size_t BOFF_NSZ  = 117307904;
constexpr size_t BOFF_WQB  = 117354240;
constexpr size_t BOFF_WPB  = 120893184;
constexpr size_t BOFF_W1B  = 122072832;
constexpr size_t BOFF_W2B  = 126791424;

// ---------------- bf16 helpers ----------------
DEVFN ushort f2b(float f) {
  union { float f; uint u; } c; c.f = f;
  uint u = c.u;
  u = (u + 0x7FFFu + ((u >> 16) & 1u)) >> 16;
  return (ushort)u;
}
DEVFN float b2f(ushort h) {
  union { uint u; float f; } c; c.u = ((uint)h) << 16;
  return c.f;
}

// ---------------- reductions ----------------
DEVFN float wave_sum(float v) {
#pragma unroll
  for (int o = 32; o; o >>= 1) v += __shfl_down(v, o, 64);
  return v;
}
DEVFN float block_sum(float v, float* red) {
  v = wave_sum(v);
  int lane = threadIdx.x & 63, wid = threadIdx.x >> 6;
  __syncthreads();
  if (lane == 0) red[wid] = v;
  __syncthreads();
  return red[0] + red[1] + red[2] + red[3];
}

// ---------------- fp32 -> bf16 convert (n % 1024 == 0) ----------------
__global__ __launch_bounds__(256) void f2b4_kernel(const float* __restrict__ src,
                                                   ushort* __restrict__ dst, int n) {
  int i = (blockIdx.x * 256 + threadIdx.x) * 4;
  if (i >= n) return;
  float4 v = *reinterpret_cast<const float4*>(src + i);
  ushort4 o;
  o.x = f2b(v.x); o.y = f2b(v.y); o.z = f2b(v.z); o.w = f2b(v.w);
  *reinterpret_cast<ushort4*>(dst + i) = o;
}

// ---------------- LayerNorm: optional fp32 + bf16 outputs ----------------
__global__ __launch_bounds__(256) void ln_kernel(
    const float* __restrict__ x, const float* __restrict__ g,
    const float* __restrict__ bb, float* __restrict__ outf,
    ushort* __restrict__ outb) {
  __shared__ float red[4];
  size_t row = blockIdx.x;
  const float* xr = x + row * DIM_;
  int tid = threadIdx.x;
  float s = 0.f;
  for (int i = tid; i < DIM_; i += 256) s += xr[i];
  s = block_sum(s, red);
  float mean = s * (1.0f / DIM_);
  float vs = 0.f;
  for (int i = tid; i < DIM_; i += 256) { float d = xr[i] - mean; vs = fmaf(d, d, vs); }
  vs = block_sum(vs, red);
  float rstd = rsqrtf(vs * (1.0f / DIM_) + 1e-5f);
  for (int i = tid; i < DIM_; i += 256) {
    float v = (xr[i] - mean) * rstd * g[i] + bb[i];
    if (outf) outf[row * DIM_ + i] = v;
    if (outb) outb[row * DIM_ + i] = f2b(v);
  }
}

// ---------------- head-averaged K weights ----------------
__global__ __launch_bounds__(256) void wkmean_kernel(const float* __restrict__ wqkv,
                                                     float* __restrict__ wkm) {
  int idx = blockIdx.x * 256 + threadIdx.x;
  if (idx >= HD_ * DIM_) return;
  int d = idx / DIM_, c = idx % DIM_;
  float s = 0.f;
  for (int h2 = 0; h2 < H_; h2++) s += wqkv[(size_t)(DIM_ + h2 * HD_ + d) * DIM_ + c];
  wkm[idx] = s * (1.0f / H_);
}

// ---------------- fp32 GEMM (kept for the index-deciding metric path) ----------------
__global__ __launch_bounds__(256) void gemm_bt(
    const float* __restrict__ A, const float* __restrict__ Bm,
    float* __restrict__ C, int M, int Nn, int K) {
  __shared__ float As[16][65];
  __shared__ float Bs[16][65];
  const int tid = threadIdx.x;
  const int tx = tid & 15, ty = tid >> 4;
  const int m0 = blockIdx.y * 64, n0 = blockIdx.x * 64;
  float acc[4][4] = {};
  for (int k0 = 0; k0 < K; k0 += 16) {
#pragma unroll
    for (int l = 0; l < 4; ++l) {
      int idx = tid + l * 256;
      int mm = idx >> 4, kk = idx & 15;
      As[kk][mm] = A[(size_t)(m0 + mm) * K + (k0 + kk)];
      Bs[kk][mm] = Bm[(size_t)(n0 + mm) * K + (k0 + kk)];
    }
    __syncthreads();
#pragma unroll
    for (int kk = 0; kk < 16; ++kk) {
      float av[4], bv[4];
#pragma unroll
      for (int i = 0; i < 4; i++) av[i] = As[kk][ty * 4 + i];
#pragma unroll
      for (int j = 0; j < 4; j++) bv[j] = Bs[kk][tx * 4 + j];
#pragma unroll
      for (int i = 0; i < 4; i++)
#pragma unroll
        for (int j = 0; j < 4; j++) acc[i][j] = fmaf(av[i], bv[j], acc[i][j]);
    }
    __syncthreads();
  }
#pragma unroll
  for (int i = 0; i < 4; i++) {
    size_t base = (size_t)(m0 + ty * 4 + i) * Nn + n0 + tx * 4;
#pragma unroll
    for (int j = 0; j < 4; j++) C[base + j] = acc[i][j];
  }
}

// ---------------- bf16 MFMA GEMM: C = act(A @ B^T + bias) (+res) ----------------
// A: [M,K] bf16 row-major; Bw: [Nn,K] bf16 row-major. Nn%128==0, K%32==0; M arbitrary.
// Tile 128x128, BK=32, 4 waves in 2x2, each wave 64x64 = 4x4 frags of 16x16x32.
__global__ __launch_bounds__(256) void gemm_mfma(
    const ushort* __restrict__ A, const ushort* __restrict__ Bw,
    const float* __restrict__ bias, const float* __restrict__ res,
    float* __restrict__ Cf, ushort* __restrict__ Cb,
    int M, int Nn, int K, int act) {
  __shared__ ushort As[128][40];  // pad 32->40: 80B row stride -> 2-way (free)
  __shared__ ushort Bs[128][40];
  const int t = threadIdx.x;
  const int wid = t >> 6, l = t & 63;
  const int wrow = wid >> 1, wcol = wid & 1;
  const int lr = l & 15, lk = l >> 4;
  const int m0 = blockIdx.y * 128, n0 = blockIdx.x * 128;
  const int srow = t >> 2, sseg = t & 3;  // staging: 64 rows x 4 segs of 8 bf16

  f32x4 acc[4][4];
#pragma unroll
  for (int i = 0; i < 4; i++)
#pragma unroll
    for (int j = 0; j < 4; j++) acc[i][j] = (f32x4){0.f, 0.f, 0.f, 0.f};

  for (int k0 = 0; k0 < K; k0 += 32) {
#pragma unroll
    for (int p = 0; p < 2; p++) {
      int row = srow + 64 * p;
      int ar = m0 + row; ar = ar < M ? ar : M - 1;  // clamp (stores guarded)
      *reinterpret_cast<uint4*>(&As[row][sseg * 8]) =
          *reinterpret_cast<const uint4*>(A + (size_t)ar * K + k0 + sseg * 8);
      *reinterpret_cast<uint4*>(&Bs[row][sseg * 8]) =
          *reinterpret_cast<const uint4*>(Bw + (size_t)(n0 + row) * K + k0 + sseg * 8);
    }
    __syncthreads();
    short8 af[4], bf[4];
#pragma unroll
    for (int mi = 0; mi < 4; mi++)
      af[mi] = *reinterpret_cast<const short8*>(&As[wrow * 64 + mi * 16 + lr][lk * 8]);
#pragma unroll
    for (int nj = 0; nj < 4; nj++)
      bf[nj] = *reinterpret_cast<const short8*>(&Bs[wcol * 64 + nj * 16 + lr][lk * 8]);
#pragma unroll
    for (int mi = 0; mi < 4; mi++)
#pragma unroll
      for (int nj = 0; nj < 4; nj++)
        acc[mi][nj] = __builtin_amdgcn_mfma_f32_16x16x32_bf16(af[mi], bf[nj], acc[mi][nj], 0, 0, 0);
    __syncthreads();
  }

  // epilogue: C/D layout col=lane&15, row=(lane>>4)*4+j  [m89/m91 verified]
#pragma unroll
  for (int mi = 0; mi < 4; mi++) {
    int rbase = m0 + wrow * 64 + mi * 16 + lk * 4;
#pragma unroll
    for (int nj = 0; nj < 4; nj++) {
      int col = n0 + wcol * 64 + nj * 16 + lr;
      float bv = bias ? bias[col] : 0.f;
#pragma unroll
      for (int j = 0; j < 4; j++) {
        int row = rbase + j;
        if (row >= M) continue;
        float v = acc[mi][nj][j] + bv;
        if (act) v = 0.5f * v * (1.0f + erff(v * 0.70710678118654752440f));
        size_t idx = (size_t)row * Nn + col;
        if (res) v += res[idx];
        if (Cf) Cf[idx] = v;
        else Cb[idx] = f2b(v);
      }
    }
  }
}

// ---------------- attention v2: one block per (b,h); K/V staged once ----------------
__global__ __launch_bounds__(256) void attn2_kernel(
    const ushort* __restrict__ qkv, const float* __restrict__ asize,
    ushort* __restrict__ o) {
  __shared__ ushort Kb[197][72];   // 144B stride -> 2-way (free)
  __shared__ ushort Vt[64][216];   // transposed V; 432B stride -> 2-way (free)
  __shared__ ushort Pb[4][216];    // per-wave P (bf16)
  __shared__ float lb[200];
  const int bh = blockIdx.x;
  const int h = bh % H_, b = bh / H_;
  const size_t bT = (size_t)b * T_;
  const int tid = threadIdx.x;
  const int lane = tid & 63, wid = tid >> 6;

  for (int j = tid; j < T_; j += 256) lb[j] = logf(asize[bT + j]);
  // stage K rows (bf16, 8-wide)
  for (int idx = tid; idx < 197 * 8; idx += 256) {
    int row = idx >> 3, seg = idx & 7;
    *reinterpret_cast<uint4*>(&Kb[row][seg * 8]) = *reinterpret_cast<const uint4*>(
        qkv + (bT + row) * (3 * DIM_) + DIM_ + h * HD_ + seg * 8);
  }
  // stage V transposed
  for (int idx = tid; idx < 197 * 8; idx += 256) {
    int row = idx >> 3, seg = idx & 7;
    uint4 v = *reinterpret_cast<const uint4*>(
        qkv + (bT + row) * (3 * DIM_) + 2 * DIM_ + h * HD_ + seg * 8);
    const ushort* us = reinterpret_cast<const ushort*>(&v);
#pragma unroll
    for (int e = 0; e < 8; e++) Vt[seg * 8 + e][row] = us[e];
  }
  // zero pad Vt cols 197..215 and Pb cols 197..215
  for (int idx = tid; idx < 64 * 19; idx += 256) Vt[idx / 19][197 + idx % 19] = 0;
  if (tid < 4 * 19) Pb[tid / 19][197 + tid % 19] = 0;
  __syncthreads();

  for (int q = wid; q < T_; q += 4) {
    // cache Q row (64 bf16) in regs via broadcast loads
    const ushort* qrow = qkv + (bT + q) * (3 * DIM_) + h * HD_;
    uint4 qreg[8];
#pragma unroll
    for (int d0 = 0; d0 < 8; d0++)
      qreg[d0] = *reinterpret_cast<const uint4*>(qrow + d0 * 8);

    float sacc[4] = {0.f, 0.f, 0.f, 0.f};
    int keyc[4];
    bool valid[4];
#pragma unroll
    for (int kr = 0; kr < 4; kr++) {
      int key = lane + kr * 64;
      valid[kr] = key < 197;
      keyc[kr] = valid[kr] ? key : 196;
    }
#pragma unroll
    for (int d0 = 0; d0 < 8; d0++) {
      const ushort* qp = reinterpret_cast<const ushort*>(&qreg[d0]);
      float qf[8];
#pragma unroll
      for (int e = 0; e < 8; e++) qf[e] = b2f(qp[e]);
#pragma unroll
      for (int kr = 0; kr < 4; kr++) {
        uint4 kv = *reinterpret_cast<const uint4*>(&Kb[keyc[kr]][d0 * 8]);
        const ushort* kp = reinterpret_cast<const ushort*>(&kv);
#pragma unroll
        for (int e = 0; e < 8; e++) sacc[kr] = fmaf(qf[e], b2f(kp[e]), sacc[kr]);
      }
    }
    float s[4], mx = -INFINITY;
#pragma unroll
    for (int kr = 0; kr < 4; kr++) {
      s[kr] = valid[kr] ? (sacc[kr] * 0.125f + lb[keyc[kr]]) : -INFINITY;
      mx = fmaxf(mx, s[kr]);
    }
#pragma unroll
    for (int off = 32; off; off >>= 1) mx = fmaxf(mx, __shfl_xor(mx, off, 64));
    float e4[4], esum = 0.f;
#pragma unroll
    for (int kr = 0; kr < 4; kr++) { e4[kr] = expf(s[kr] - mx); esum += e4[kr]; }
#pragma unroll
    for (int off = 32; off; off >>= 1) esum += __shfl_xor(esum, off, 64);
    float inv = 1.0f / esum;
#pragma unroll
    for (int kr = 0; kr < 4; kr++)
      if (valid[kr]) Pb[wid][keyc[kr]] = f2b(e4[kr] * inv);

    // PV: lane = output dim d
    float oacc = 0.f;
#pragma unroll
    for (int j0 = 0; j0 < 25; j0++) {
      uint4 pv = *reinterpret_cast<const uint4*>(&Pb[wid][j0 * 8]);  // broadcast
      uint4 vv = *reinterpret_cast<const uint4*>(&Vt[lane][j0 * 8]);
      const ushort* pp = reinterpret_cast<const ushort*>(&pv);
      const ushort* vp = reinterpret_cast<const ushort*>(&vv);
#pragma unroll
      for (int e = 0; e < 8; e++) oacc = fmaf(b2f(pp[e]), b2f(vp[e]), oacc);
    }
    o[(bT + q) * DIM_ + h * HD_ + lane] = f2b(oacc);
  }
}

// ---------------- ToMe matching (fp32, unchanged — decision-critical) ----------------
__global__ __launch_bounds__(256) void match_kernel(
    const float* __restrict__ metric, const float* __restrict__ asize,
    int* __restrict__ route, float* __restrict__ nsz,
    float* __restrict__ out_ns, float* __restrict__ out_rci) {
  __shared__ float m[197][65];
  __shared__ float nmax[99];
  __shared__ int nidx[99];
  __shared__ int rnk[99];
  __shared__ int srcr[16];
  __shared__ int dstr[16];
  __shared__ int unmp[99];
  int b = blockIdx.x;
  int tid = threadIdx.x;
  int lane = tid & 63, wid = tid >> 6;

  if (tid < T_) {
    const float* mr = metric + ((size_t)b * T_ + tid) * HD_;
    float ss = 0.f;
#pragma unroll
    for (int d = 0; d < 64; d++) { float v = mr[d]; ss = fmaf(v, v, ss); }
    float nrm = sqrtf(ss);
#pragma unroll
    for (int d = 0; d < 64; d++) m[tid][d] = mr[d] / nrm;
  }
  __syncthreads();

  for (int i = wid; i < NE_; i += 4) {
    if (i == 0) {
      if (lane == 0) { nmax[0] = -INFINITY; nidx[0] = 0; }
      continue;
    }
    float bv = -INFINITY;
    int bj = 1 << 30;
    for (int j = lane; j < NO_; j += 64) {
      const float* a = m[2 * i];
      const float* bb = m[2 * j + 1];
      float sdot = 0.f;
#pragma unroll
      for (int d = 0; d < 64; d++) sdot = fmaf(a[d], bb[d], sdot);
      if (sdot > bv) { bv = sdot; bj = j; }
    }
#pragma unroll
    for (int off = 32; off; off >>= 1) {
      float ov = __shfl_down(bv, off, 64);
      int oj = __shfl_down(bj, off, 64);
      if (ov > bv || (ov == bv && oj < bj)) { bv = ov; bj = oj; }
    }
    if (lane == 0) { nmax[i] = bv; nidx[i] = bj; }
  }
  __syncthreads();

  if (tid < NE_) {
    float v = nmax[tid];
    int r = 0;
    for (int i2 = 0; i2 < NE_; i2++) {
      float v2 = nmax[i2];
      r += (v2 > v) || (v2 == v && i2 < tid);
    }
    rnk[tid] = r;
  }
  __syncthreads();
  if (tid < NE_ && rnk[tid] < REFF_) { srcr[rnk[tid]] = tid; dstr[rnk[tid]] = nidx[tid]; }
  __syncthreads();
  if (tid < NE_ && rnk[tid] >= REFF_) {
    int p = 0;
    for (int i2 = 0; i2 < tid; i2++) p += (rnk[i2] >= REFF_);
    unmp[tid] = p;
    int* rr = route + ((size_t)b * TM_ + p) * 18;
    rr[0] = 1;
    rr[1] = 2 * tid;
  }
  if (tid < NO_) {
    int d = tid;
    int* rr = route + ((size_t)b * TM_ + (NE_ - REFF_) + d) * 18;
    int cnt = 1;
    rr[1] = 2 * d + 1;
    for (int r = 0; r < REFF_; r++)
      if (dstr[r] == d) { cnt++; rr[cnt] = 2 * srcr[r]; }
    rr[0] = cnt;
  }
  __syncthreads();

  for (int row = tid; row < TM_; row += 256) {
    const int* rr = route + ((size_t)b * TM_ + row) * 18;
    int cnt = rr[0];
    float s = 0.f;
    for (int t2 = 0; t2 < cnt; t2++) s += asize[(size_t)b * T_ + rr[1 + t2]];
    out_ns[(size_t)b * TM_ + row] = s;
    nsz[(size_t)b * TM_ + row] = s;
  }
  for (int t = 1 + tid; t < T_; t += 256) {
    int val;
    if (t & 1) {
      val = (NE_ - REFF_ - 1) + ((t - 1) >> 1);
    } else {
      int i = t >> 1;
      val = (rnk[i] >= REFF_) ? (unmp[i] - 1) : ((NE_ - REFF_ - 1) + nidx[i]);
    }
    out_rci[(size_t)b * (T_ - 1) + (t - 1)] = (float)val;
  }
}

// ---------------- merged x = merge(x1 * size) / new_size ----------------
__global__ __launch_bounds__(256) void merge_x_kernel(
    const float* __restrict__ x1, const float* __restrict__ asize,
    const int* __restrict__ route, const float* __restrict__ nsz,
    float* __restrict__ xm) {
  int row = blockIdx.x;
  int b = row / TM_;
  const int* rr = route + (size_t)row * 18;
  __shared__ int cnt_s;
  __shared__ int toks[17];
  __shared__ float szs[17];
  int tid = threadIdx.x;
  if (tid == 0) cnt_s = rr[0];
  __syncthreads();
  int cnt = cnt_s;
  if (tid < cnt) {
    int t = rr[1 + tid];
    toks[tid] = t;
    szs[tid] = asize[(size_t)b * T_ + t];
  }
  __syncthreads();
  float ns = nsz[row];
  for (int e = tid; e < DIM_; e += 256) {
    float acc = 0.f;
    for (int c2 = 0; c2 < cnt; c2++)
      acc = fmaf(x1[((size_t)b * T_ + toks[c2]) * DIM_ + e], szs[c2], acc);
    xm[(size_t)row * DIM_ + e] = acc / ns;
  }
}

// ---------------- launch ----------------
extern "C" void kernel_launch(void* const* d_in, const int* in_sizes, int n_in,
                              void* d_out, int out_size, void* d_ws, size_t ws_size,
                              hipStream_t stream) {
  const float* x_in = (const float*)d_in[0];
  const float* asize = (const float*)d_in[1];
  const float* ln1g = (const float*)d_in[2];
  const float* ln1b = (const float*)d_in[3];
  const float* wqkv = (const float*)d_in[4];
  const float* wproj = (const float*)d_in[5];
  const float* bproj = (const float*)d_in[6];
  const float* ln2g = (const float*)d_in[7];
  const float* ln2b = (const float*)d_in[8];
  const float* wfc1 = (const float*)d_in[9];
  const float* bfc1 = (const float*)d_in[10];
  const float* wfc2 = (const float*)d_in[11];
  const float* bfc2 = (const float*)d_in[12];

  char* base = (char*)d_ws;
  float* h    = (float*)(base + BOFF_A);
  ushort* qkvb = (ushort*)(base + BOFF_A);
  float* x1   = (float*)(base + BOFF_A);
  ushort* h2b = (ushort*)(base + BOFF_A);
  ushort* gbc = (ushort*)(base + BOFF_GBC);
  ushort* hb  = (ushort*)(base + BOFF_B);
  ushort* ob  = (ushort*)(base + BOFF_B);
  float* xm   = (float*)(base + BOFF_C);
  float* met  = (float*)(base + BOFF_D);
  float* wkm  = (float*)(base + BOFF_WKM);
  int* route  = (int*)(base + BOFF_RT);
  float* nsz  = (float*)(base + BOFF_NSZ);
  ushort* wqb = (ushort*)(base + BOFF_WQB);
  ushort* wpb = (ushort*)(base + BOFF_WPB);
  ushort* w1b = (ushort*)(base + BOFF_W1B);
  ushort* w2b = (ushort*)(base + BOFF_W2B);

  float* out_x = (float*)d_out;
  float* out_ns = out_x + (size_t)NM_ * DIM_;
  float* out_rci = out_ns + NM_;

  // weight conversions (bf16)
  f2b4_kernel<<<(3 * DIM_ * DIM_) / 1024, 256, 0, stream>>>(wqkv, wqb, 3 * DIM_ * DIM_);
  f2b4_kernel<<<(DIM_ * DIM_) / 1024, 256, 0, stream>>>(wproj, wpb, DIM_ * DIM_);
  f2b4_kernel<<<(MLP_ * DIM_) / 1024, 256, 0, stream>>>(wfc1, w1b, MLP_ * DIM_);
  f2b4_kernel<<<(DIM_ * MLP_) / 1024, 256, 0, stream>>>(wfc2, w2b, DIM_ * MLP_);
  wkmean_kernel<<<(HD_ * DIM_ + 255) / 256, 256, 0, stream>>>(wqkv, wkm);

  // LN1 -> h (fp32, for metric) + hb (bf16, for qkv GEMM)
  ln_kernel<<<N_, 256, 0, stream>>>(x_in, ln1g, ln1b, h, hb);
  // metric GEMM stays fp32 (decision-critical); must run before qkv_b overlays h
  gemm_bt<<<dim3(1, N_ / 64), 256, 0, stream>>>(h, wkm, met, N_, HD_, DIM_);
  // qkv = hb @ wqkv^T (bf16 out)
  gemm_mfma<<<dim3(3 * DIM_ / 128, (N_ + 127) / 128), 256, 0, stream>>>(
      hb, wqb, nullptr, nullptr, nullptr, qkvb, N_, 3 * DIM_, DIM_, 0);
  attn2_kernel<<<B_ * H_, 256, 0, stream>>>(qkvb, asize, ob);
  // x1 = ob @ wproj^T + bproj + x_in (fp32 out)
  gemm_mfma<<<dim3(DIM_ / 128, (N_ + 127) / 128), 256, 0, stream>>>(
      ob, wpb, bproj, x_in, x1, nullptr, N_, DIM_, DIM_, 0);
  match_kernel<<<B_, 256, 0, stream>>>(met, asize, route, nsz, out_ns, out_rci);
  merge_x_kernel<<<NM_, 256, 0, stream>>>(x1, asize, route, nsz, xm);
  ln_kernel<<<NM_, 256, 0, stream>>>(xm, ln2g, ln2b, nullptr, h2b);

  // MLP in 2 row-chunks (fc1 -> gelu -> bf16 gbc; fc2 + residual -> out fp32)
  int r0 = 0;
  for (int c = 0; c < 2; c++) {
    int rows = (c == 0) ? MCH_ : (NM_ - MCH_);
    const ushort* h2c = h2b + (size_t)r0 * DIM_;
    const float* xmc = xm + (size_t)r0 * DIM_;
    float* outc = out_x + (size_t)r0 * DIM_;
    gemm_mfma<<<dim3(MLP_ / 128, (rows + 127) / 128), 256, 0, stream>>>(
        h2c, w1b, bfc1, nullptr, nullptr, gbc, rows, MLP_, DIM_, 1);
    gemm_mfma<<<dim3(DIM_ / 128, (rows + 127) / 128), 256, 0, stream>>>(
        gbc, w2b, bfc2, xmc, outc, nullptr, rows, DIM_, MLP_, 0);
    r0 += rows;
  }
}

// Round 4
// 793.914 us; speedup vs baseline: 6.5987x; 1.6164x over previous
//
#include <hip/hip_runtime.h>
#include <cstdint>
#include <cstddef>

#define DEVFN __device__ __forceinline__

typedef __attribute__((ext_vector_type(8))) short short8;
typedef __attribute__((ext_vector_type(4))) float f32x4;

// Problem constants
constexpr int B_ = 64, T_ = 197, DIM_ = 768, H_ = 12, HD_ = 64, MLP_ = 3072;
constexpr int N_ = B_ * T_;          // 12608 tokens
constexpr int NE_ = 99, NO_ = 98, REFF_ = 16;
constexpr int TM_ = (NE_ - REFF_) + NO_;  // 181 merged tokens
constexpr int NM_ = B_ * TM_;        // 11584 merged rows
constexpr int MCH_ = 5792;           // MLP row chunk (2 chunks)

// ---------------- workspace layout (BYTE offsets; all 16B-aligned) ----------------
constexpr size_t BOFF_A    = 0;
constexpr size_t BOFF_GBC  = 17793024;   // inside A, after h2b
constexpr size_t BOFF_B    = 58097664;
constexpr size_t BOFF_C    = 77463552;
constexpr size_t BOFF_D    = 113049600;
constexpr size_t BOFF_WKM  = 116277248;
constexpr size_t BOFF_RT   = 116473856;
constexpr size_t BOFF_NSZ  = 117307904;
constexpr size_t BOFF_WQB  = 117354240;
constexpr size_t BOFF_WPB  = 120893184;
constexpr size_t BOFF_W1B  = 122072832;
constexpr size_t BOFF_W2B  = 126791424;

// ---------------- bf16 helpers ----------------
DEVFN ushort f2b(float f) {
  union { float f; uint u; } c; c.f = f;
  uint u = c.u;
  u = (u + 0x7FFFu + ((u >> 16) & 1u)) >> 16;
  return (ushort)u;
}
DEVFN float b2f(ushort h) {
  union { uint u; float f; } c; c.u = ((uint)h) << 16;
  return c.f;
}

// ---------------- reductions ----------------
DEVFN float wave_sum(float v) {
#pragma unroll
  for (int o = 32; o; o >>= 1) v += __shfl_down(v, o, 64);
  return v;
}
DEVFN float block_sum(float v, float* red) {
  v = wave_sum(v);
  int lane = threadIdx.x & 63, wid = threadIdx.x >> 6;
  __syncthreads();
  if (lane == 0) red[wid] = v;
  __syncthreads();
  return red[0] + red[1] + red[2] + red[3];
}

// ---------------- fp32 -> bf16 convert ----------------
__global__ __launch_bounds__(256) void f2b4_kernel(const float* __restrict__ src,
                                                   ushort* __restrict__ dst, int n) {
  int i = (blockIdx.x * 256 + threadIdx.x) * 4;
  if (i >= n) return;
  float4 v = *reinterpret_cast<const float4*>(src + i);
  ushort4 o;
  o.x = f2b(v.x); o.y = f2b(v.y); o.z = f2b(v.z); o.w = f2b(v.w);
  *reinterpret_cast<ushort4*>(dst + i) = o;
}

// ---------------- LayerNorm: optional fp32 + bf16 outputs ----------------
__global__ __launch_bounds__(256) void ln_kernel(
    const float* __restrict__ x, const float* __restrict__ g,
    const float* __restrict__ bb, float* __restrict__ outf,
    ushort* __restrict__ outb) {
  __shared__ float red[4];
  size_t row = blockIdx.x;
  const float* xr = x + row * DIM_;
  int tid = threadIdx.x;
  float s = 0.f;
  for (int i = tid; i < DIM_; i += 256) s += xr[i];
  s = block_sum(s, red);
  float mean = s * (1.0f / DIM_);
  float vs = 0.f;
  for (int i = tid; i < DIM_; i += 256) { float d = xr[i] - mean; vs = fmaf(d, d, vs); }
  vs = block_sum(vs, red);
  float rstd = rsqrtf(vs * (1.0f / DIM_) + 1e-5f);
  for (int i = tid; i < DIM_; i += 256) {
    float v = (xr[i] - mean) * rstd * g[i] + bb[i];
    if (outf) outf[row * DIM_ + i] = v;
    if (outb) outb[row * DIM_ + i] = f2b(v);
  }
}

// ---------------- head-averaged K weights ----------------
__global__ __launch_bounds__(256) void wkmean_kernel(const float* __restrict__ wqkv,
                                                     float* __restrict__ wkm) {
  int idx = blockIdx.x * 256 + threadIdx.x;
  if (idx >= HD_ * DIM_) return;
  int d = idx / DIM_, c = idx % DIM_;
  float s = 0.f;
  for (int h2 = 0; h2 < H_; h2++) s += wqkv[(size_t)(DIM_ + h2 * HD_ + d) * DIM_ + c];
  wkm[idx] = s * (1.0f / H_);
}

// ---------------- fp32 GEMM (kept for the index-deciding metric path) ----------------
__global__ __launch_bounds__(256) void gemm_bt(
    const float* __restrict__ A, const float* __restrict__ Bm,
    float* __restrict__ C, int M, int Nn, int K) {
  __shared__ float As[16][65];
  __shared__ float Bs[16][65];
  const int tid = threadIdx.x;
  const int tx = tid & 15, ty = tid >> 4;
  const int m0 = blockIdx.y * 64, n0 = blockIdx.x * 64;
  float acc[4][4] = {};
  for (int k0 = 0; k0 < K; k0 += 16) {
#pragma unroll
    for (int l = 0; l < 4; ++l) {
      int idx = tid + l * 256;
      int mm = idx >> 4, kk = idx & 15;
      As[kk][mm] = A[(size_t)(m0 + mm) * K + (k0 + kk)];
      Bs[kk][mm] = Bm[(size_t)(n0 + mm) * K + (k0 + kk)];
    }
    __syncthreads();
#pragma unroll
    for (int kk = 0; kk < 16; ++kk) {
      float av[4], bv[4];
#pragma unroll
      for (int i = 0; i < 4; i++) av[i] = As[kk][ty * 4 + i];
#pragma unroll
      for (int j = 0; j < 4; j++) bv[j] = Bs[kk][tx * 4 + j];
#pragma unroll
      for (int i = 0; i < 4; i++)
#pragma unroll
        for (int j = 0; j < 4; j++) acc[i][j] = fmaf(av[i], bv[j], acc[i][j]);
    }
    __syncthreads();
  }
#pragma unroll
  for (int i = 0; i < 4; i++) {
    size_t base = (size_t)(m0 + ty * 4 + i) * Nn + n0 + tx * 4;
#pragma unroll
    for (int j = 0; j < 4; j++) C[base + j] = acc[i][j];
  }
}

// ---------------- bf16 MFMA GEMM: C = act(A @ B^T + bias) (+res) ----------------
__global__ __launch_bounds__(256) void gemm_mfma(
    const ushort* __restrict__ A, const ushort* __restrict__ Bw,
    const float* __restrict__ bias, const float* __restrict__ res,
    float* __restrict__ Cf, ushort* __restrict__ Cb,
    int M, int Nn, int K, int act) {
  __shared__ ushort As[128][40];  // pad 32->40: 80B row stride -> 2-way (free)
  __shared__ ushort Bs[128][40];
  const int t = threadIdx.x;
  const int wid = t >> 6, l = t & 63;
  const int wrow = wid >> 1, wcol = wid & 1;
  const int lr = l & 15, lk = l >> 4;
  const int m0 = blockIdx.y * 128, n0 = blockIdx.x * 128;
  const int srow = t >> 2, sseg = t & 3;

  f32x4 acc[4][4];
#pragma unroll
  for (int i = 0; i < 4; i++)
#pragma unroll
    for (int j = 0; j < 4; j++) acc[i][j] = (f32x4){0.f, 0.f, 0.f, 0.f};

  for (int k0 = 0; k0 < K; k0 += 32) {
#pragma unroll
    for (int p = 0; p < 2; p++) {
      int row = srow + 64 * p;
      int ar = m0 + row; ar = ar < M ? ar : M - 1;
      *reinterpret_cast<uint4*>(&As[row][sseg * 8]) =
          *reinterpret_cast<const uint4*>(A + (size_t)ar * K + k0 + sseg * 8);
      *reinterpret_cast<uint4*>(&Bs[row][sseg * 8]) =
          *reinterpret_cast<const uint4*>(Bw + (size_t)(n0 + row) * K + k0 + sseg * 8);
    }
    __syncthreads();
    short8 af[4], bf[4];
#pragma unroll
    for (int mi = 0; mi < 4; mi++)
      af[mi] = *reinterpret_cast<const short8*>(&As[wrow * 64 + mi * 16 + lr][lk * 8]);
#pragma unroll
    for (int nj = 0; nj < 4; nj++)
      bf[nj] = *reinterpret_cast<const short8*>(&Bs[wcol * 64 + nj * 16 + lr][lk * 8]);
#pragma unroll
    for (int mi = 0; mi < 4; mi++)
#pragma unroll
      for (int nj = 0; nj < 4; nj++)
        acc[mi][nj] = __builtin_amdgcn_mfma_f32_16x16x32_bf16(af[mi], bf[nj], acc[mi][nj], 0, 0, 0);
    __syncthreads();
  }

#pragma unroll
  for (int mi = 0; mi < 4; mi++) {
    int rbase = m0 + wrow * 64 + mi * 16 + lk * 4;
#pragma unroll
    for (int nj = 0; nj < 4; nj++) {
      int col = n0 + wcol * 64 + nj * 16 + lr;
      float bv = bias ? bias[col] : 0.f;
#pragma unroll
      for (int j = 0; j < 4; j++) {
        int row = rbase + j;
        if (row >= M) continue;
        float v = acc[mi][nj][j] + bv;
        if (act) v = 0.5f * v * (1.0f + erff(v * 0.70710678118654752440f));
        size_t idx = (size_t)row * Nn + col;
        if (res) v += res[idx];
        if (Cf) Cf[idx] = v;
        else Cb[idx] = f2b(v);
      }
    }
  }
}

// ---------------- attention v3: MFMA flash-style, one block per (b,h) ----------------
// 8 waves x 512 threads. K[208][72] + Vt[64][232] staged once; each wave owns a
// 16-query strip: QK^T via 13x2 MFMA, in-register softmax (C/D layout:
// col=lane&15, row=(lane>>4)*4+j), P -> per-wave LDS strip, PV via 7x4 MFMA.
__global__ __launch_bounds__(512) void attn3_kernel(
    const ushort* __restrict__ qkv, const float* __restrict__ asize,
    ushort* __restrict__ o) {
  __shared__ ushort Kb[208][72];       // 144B stride
  __shared__ ushort Vt[64][232];       // 464B stride; V transposed
  __shared__ ushort Plds[8][16][232];  // per-wave P strip
  __shared__ float lb[200];
  const int bh = blockIdx.x;
  const int h = bh % H_, b = bh / H_;
  const size_t bT = (size_t)b * T_;
  const int tid = threadIdx.x;
  const int l = tid & 63, wid = tid >> 6;
  const int lr = l & 15, lk = l >> 4;

  for (int j = tid; j < T_; j += 512) lb[j] = logf(asize[bT + j]);
  // stage K rows (clamped >=197 -> dup row 196; cols masked later)
  for (int idx = tid; idx < 208 * 8; idx += 512) {
    int row = idx >> 3, seg = idx & 7;
    int kr = row < T_ ? row : T_ - 1;
    *reinterpret_cast<uint4*>(&Kb[row][seg * 8]) = *reinterpret_cast<const uint4*>(
        qkv + (bT + kr) * (3 * DIM_) + DIM_ + h * HD_ + seg * 8);
  }
  // stage V transposed
  for (int idx = tid; idx < 197 * 8; idx += 512) {
    int row = idx >> 3, seg = idx & 7;
    uint4 v = *reinterpret_cast<const uint4*>(
        qkv + (bT + row) * (3 * DIM_) + 2 * DIM_ + h * HD_ + seg * 8);
    const ushort* us = reinterpret_cast<const ushort*>(&v);
#pragma unroll
    for (int e = 0; e < 8; e++) Vt[seg * 8 + e][row] = us[e];
  }
  // zero Vt pad cols 197..231 (avoid 0*garbage=NaN in MFMA)
  for (int idx = tid; idx < 64 * 35; idx += 512) Vt[idx / 35][197 + idx % 35] = 0;
  // zero all of Plds once (cols >= 208 never rewritten)
  for (int i = tid; i < 8 * 16 * 116; i += 512) reinterpret_cast<uint*>(Plds)[i] = 0;
  __syncthreads();

  for (int s = wid; s < 13; s += 8) {
    const int q0 = s * 16;
    // Q A-frags straight from global (row-major [16][64] slice)
    int qr = q0 + lr; qr = qr < T_ ? qr : T_ - 1;
    const ushort* qp = qkv + (bT + qr) * (3 * DIM_) + h * HD_;
    short8 aq0 = *reinterpret_cast<const short8*>(qp + lk * 8);
    short8 aq1 = *reinterpret_cast<const short8*>(qp + 32 + lk * 8);

    f32x4 accs[13];
#pragma unroll
    for (int t2 = 0; t2 < 13; t2++) accs[t2] = (f32x4){0.f, 0.f, 0.f, 0.f};
#pragma unroll
    for (int t2 = 0; t2 < 13; t2++) {
      short8 bk0 = *reinterpret_cast<const short8*>(&Kb[t2 * 16 + lr][lk * 8]);
      short8 bk1 = *reinterpret_cast<const short8*>(&Kb[t2 * 16 + lr][32 + lk * 8]);
      accs[t2] = __builtin_amdgcn_mfma_f32_16x16x32_bf16(aq0, bk0, accs[t2], 0, 0, 0);
      accs[t2] = __builtin_amdgcn_mfma_f32_16x16x32_bf16(aq1, bk1, accs[t2], 0, 0, 0);
    }
    // scale + bias + mask; in-register row softmax.
    // lane holds S[row=lk*4+j][col=t*16+lr]; row-reduce = shfl_xor over 16-lane group.
    const int col0 = lr;  // within-tile col
    float m4[4] = {-INFINITY, -INFINITY, -INFINITY, -INFINITY};
#pragma unroll
    for (int t2 = 0; t2 < 13; t2++) {
      int col = t2 * 16 + col0;
      bool valid = col < T_;
      float lbv = valid ? lb[col] : 0.f;
#pragma unroll
      for (int j = 0; j < 4; j++) {
        float v = valid ? fmaf(accs[t2][j], 0.125f, lbv) : -INFINITY;
        accs[t2][j] = v;
        m4[j] = fmaxf(m4[j], v);
      }
    }
#pragma unroll
    for (int off = 1; off < 16; off <<= 1)
#pragma unroll
      for (int j = 0; j < 4; j++) m4[j] = fmaxf(m4[j], __shfl_xor(m4[j], off, 64));
    float s4[4] = {0.f, 0.f, 0.f, 0.f};
#pragma unroll
    for (int t2 = 0; t2 < 13; t2++)
#pragma unroll
      for (int j = 0; j < 4; j++) {
        float e = __expf(accs[t2][j] - m4[j]);
        accs[t2][j] = e;
        s4[j] += e;
      }
#pragma unroll
    for (int off = 1; off < 16; off <<= 1)
#pragma unroll
      for (int j = 0; j < 4; j++) s4[j] += __shfl_xor(s4[j], off, 64);
    float inv4[4];
#pragma unroll
    for (int j = 0; j < 4; j++) inv4[j] = 1.0f / s4[j];
    // write P strip (bf16) to per-wave LDS
#pragma unroll
    for (int t2 = 0; t2 < 13; t2++)
#pragma unroll
      for (int j = 0; j < 4; j++)
        Plds[wid][lk * 4 + j][t2 * 16 + col0] = f2b(accs[t2][j] * inv4[j]);

    // PV: O[16][64] = P[16][224] @ Vt^T
    f32x4 acco[4];
#pragma unroll
    for (int ct = 0; ct < 4; ct++) acco[ct] = (f32x4){0.f, 0.f, 0.f, 0.f};
#pragma unroll
    for (int kt = 0; kt < 7; kt++) {
      short8 ap = *reinterpret_cast<const short8*>(&Plds[wid][lr][kt * 32 + lk * 8]);
#pragma unroll
      for (int ct = 0; ct < 4; ct++) {
        short8 bv = *reinterpret_cast<const short8*>(&Vt[ct * 16 + lr][kt * 32 + lk * 8]);
        acco[ct] = __builtin_amdgcn_mfma_f32_16x16x32_bf16(ap, bv, acco[ct], 0, 0, 0);
      }
    }
#pragma unroll
    for (int ct = 0; ct < 4; ct++)
#pragma unroll
      for (int j = 0; j < 4; j++) {
        int row = q0 + lk * 4 + j;
        if (row < T_)
          o[(bT + row) * DIM_ + h * HD_ + ct * 16 + lr] = f2b(acco[ct][j]);
      }
  }
}

// ---------------- ToMe matching (fp32, decision-critical) ----------------
__global__ __launch_bounds__(256) void match_kernel(
    const float* __restrict__ metric, const float* __restrict__ asize,
    int* __restrict__ route, float* __restrict__ nsz,
    float* __restrict__ out_ns, float* __restrict__ out_rci) {
  __shared__ float m[197][65];
  __shared__ float nmax[99];
  __shared__ int nidx[99];
  __shared__ int rnk[99];
  __shared__ int srcr[16];
  __shared__ int dstr[16];
  __shared__ int unmp[99];
  int b = blockIdx.x;
  int tid = threadIdx.x;
  int lane = tid & 63, wid = tid >> 6;

  if (tid < T_) {
    const float* mr = metric + ((size_t)b * T_ + tid) * HD_;
    float ss = 0.f;
#pragma unroll
    for (int d = 0; d < 64; d++) { float v = mr[d]; ss = fmaf(v, v, ss); }
    float nrm = sqrtf(ss);
#pragma unroll
    for (int d = 0; d < 64; d++) m[tid][d] = mr[d] / nrm;
  }
  __syncthreads();

  for (int i = wid; i < NE_; i += 4) {
    if (i == 0) {
      if (lane == 0) { nmax[0] = -INFINITY; nidx[0] = 0; }
      continue;
    }
    float bv = -INFINITY;
    int bj = 1 << 30;
    for (int j = lane; j < NO_; j += 64) {
      const float* a = m[2 * i];
      const float* bb = m[2 * j + 1];
      float sdot = 0.f;
#pragma unroll
      for (int d = 0; d < 64; d++) sdot = fmaf(a[d], bb[d], sdot);
      if (sdot > bv) { bv = sdot; bj = j; }
    }
#pragma unroll
    for (int off = 32; off; off >>= 1) {
      float ov = __shfl_down(bv, off, 64);
      int oj = __shfl_down(bj, off, 64);
      if (ov > bv || (ov == bv && oj < bj)) { bv = ov; bj = oj; }
    }
    if (lane == 0) { nmax[i] = bv; nidx[i] = bj; }
  }
  __syncthreads();

  if (tid < NE_) {
    float v = nmax[tid];
    int r = 0;
    for (int i2 = 0; i2 < NE_; i2++) {
      float v2 = nmax[i2];
      r += (v2 > v) || (v2 == v && i2 < tid);
    }
    rnk[tid] = r;
  }
  __syncthreads();
  if (tid < NE_ && rnk[tid] < REFF_) { srcr[rnk[tid]] = tid; dstr[rnk[tid]] = nidx[tid]; }
  __syncthreads();
  if (tid < NE_ && rnk[tid] >= REFF_) {
    int p = 0;
    for (int i2 = 0; i2 < tid; i2++) p += (rnk[i2] >= REFF_);
    unmp[tid] = p;
    int* rr = route + ((size_t)b * TM_ + p) * 18;
    rr[0] = 1;
    rr[1] = 2 * tid;
  }
  if (tid < NO_) {
    int d = tid;
    int* rr = route + ((size_t)b * TM_ + (NE_ - REFF_) + d) * 18;
    int cnt = 1;
    rr[1] = 2 * d + 1;
    for (int r = 0; r < REFF_; r++)
      if (dstr[r] == d) { cnt++; rr[cnt] = 2 * srcr[r]; }
    rr[0] = cnt;
  }
  __syncthreads();

  for (int row = tid; row < TM_; row += 256) {
    const int* rr = route + ((size_t)b * TM_ + row) * 18;
    int cnt = rr[0];
    float s = 0.f;
    for (int t2 = 0; t2 < cnt; t2++) s += asize[(size_t)b * T_ + rr[1 + t2]];
    out_ns[(size_t)b * TM_ + row] = s;
    nsz[(size_t)b * TM_ + row] = s;
  }
  for (int t = 1 + tid; t < T_; t += 256) {
    int val;
    if (t & 1) {
      val = (NE_ - REFF_ - 1) + ((t - 1) >> 1);
    } else {
      int i = t >> 1;
      val = (rnk[i] >= REFF_) ? (unmp[i] - 1) : ((NE_ - REFF_ - 1) + nidx[i]);
    }
    out_rci[(size_t)b * (T_ - 1) + (t - 1)] = (float)val;
  }
}

// ---------------- merged x = merge(x1 * size) / new_size ----------------
__global__ __launch_bounds__(256) void merge_x_kernel(
    const float* __restrict__ x1, const float* __restrict__ asize,
    const int* __restrict__ route, const float* __restrict__ nsz,
    float* __restrict__ xm) {
  int row = blockIdx.x;
  int b = row / TM_;
  const int* rr = route + (size_t)row * 18;
  __shared__ int cnt_s;
  __shared__ int toks[17];
  __shared__ float szs[17];
  int tid = threadIdx.x;
  if (tid == 0) cnt_s = rr[0];
  __syncthreads();
  int cnt = cnt_s;
  if (tid < cnt) {
    int t = rr[1 + tid];
    toks[tid] = t;
    szs[tid] = asize[(size_t)b * T_ + t];
  }
  __syncthreads();
  float ns = nsz[row];
  for (int e = tid; e < DIM_; e += 256) {
    float acc = 0.f;
    for (int c2 = 0; c2 < cnt; c2++)
      acc = fmaf(x1[((size_t)b * T_ + toks[c2]) * DIM_ + e], szs[c2], acc);
    xm[(size_t)row * DIM_ + e] = acc / ns;
  }
}

// ---------------- launch ----------------
extern "C" void kernel_launch(void* const* d_in, const int* in_sizes, int n_in,
                              void* d_out, int out_size, void* d_ws, size_t ws_size,
                              hipStream_t stream) {
  const float* x_in = (const float*)d_in[0];
  const float* asize = (const float*)d_in[1];
  const float* ln1g = (const float*)d_in[2];
  const float* ln1b = (const float*)d_in[3];
  const float* wqkv = (const float*)d_in[4];
  const float* wproj = (const float*)d_in[5];
  const float* bproj = (const float*)d_in[6];
  const float* ln2g = (const float*)d_in[7];
  const float* ln2b = (const float*)d_in[8];
  const float* wfc1 = (const float*)d_in[9];
  const float* bfc1 = (const float*)d_in[10];
  const float* wfc2 = (const float*)d_in[11];
  const float* bfc2 = (const float*)d_in[12];

  char* base = (char*)d_ws;
  float* h    = (float*)(base + BOFF_A);
  ushort* qkvb = (ushort*)(base + BOFF_A);
  float* x1   = (float*)(base + BOFF_A);
  ushort* h2b = (ushort*)(base + BOFF_A);
  ushort* gbc = (ushort*)(base + BOFF_GBC);
  ushort* hb  = (ushort*)(base + BOFF_B);
  ushort* ob  = (ushort*)(base + BOFF_B);
  float* xm   = (float*)(base + BOFF_C);
  float* met  = (float*)(base + BOFF_D);
  float* wkm  = (float*)(base + BOFF_WKM);
  int* route  = (int*)(base + BOFF_RT);
  float* nsz  = (float*)(base + BOFF_NSZ);
  ushort* wqb = (ushort*)(base + BOFF_WQB);
  ushort* wpb = (ushort*)(base + BOFF_WPB);
  ushort* w1b = (ushort*)(base + BOFF_W1B);
  ushort* w2b = (ushort*)(base + BOFF_W2B);

  float* out_x = (float*)d_out;
  float* out_ns = out_x + (size_t)NM_ * DIM_;
  float* out_rci = out_ns + NM_;

  f2b4_kernel<<<(3 * DIM_ * DIM_) / 1024, 256, 0, stream>>>(wqkv, wqb, 3 * DIM_ * DIM_);
  f2b4_kernel<<<(DIM_ * DIM_) / 1024, 256, 0, stream>>>(wproj, wpb, DIM_ * DIM_);
  f2b4_kernel<<<(MLP_ * DIM_) / 1024, 256, 0, stream>>>(wfc1, w1b, MLP_ * DIM_);
  f2b4_kernel<<<(DIM_ * MLP_) / 1024, 256, 0, stream>>>(wfc2, w2b, DIM_ * MLP_);
  wkmean_kernel<<<(HD_ * DIM_ + 255) / 256, 256, 0, stream>>>(wqkv, wkm);

  ln_kernel<<<N_, 256, 0, stream>>>(x_in, ln1g, ln1b, h, hb);
  gemm_bt<<<dim3(1, N_ / 64), 256, 0, stream>>>(h, wkm, met, N_, HD_, DIM_);
  gemm_mfma<<<dim3(3 * DIM_ / 128, (N_ + 127) / 128), 256, 0, stream>>>(
      hb, wqb, nullptr, nullptr, nullptr, qkvb, N_, 3 * DIM_, DIM_, 0);
  attn3_kernel<<<B_ * H_, 512, 0, stream>>>(qkvb, asize, ob);
  gemm_mfma<<<dim3(DIM_ / 128, (N_ + 127) / 128), 256, 0, stream>>>(
      ob, wpb, bproj, x_in, x1, nullptr, N_, DIM_, DIM_, 0);
  match_kernel<<<B_, 256, 0, stream>>>(met, asize, route, nsz, out_ns, out_rci);
  merge_x_kernel<<<NM_, 256, 0, stream>>>(x1, asize, route, nsz, xm);
  ln_kernel<<<NM_, 256, 0, stream>>>(xm, ln2g, ln2b, nullptr, h2b);

  int r0 = 0;
  for (int c = 0; c < 2; c++) {
    int rows = (c == 0) ? MCH_ : (NM_ - MCH_);
    const ushort* h2c = h2b + (size_t)r0 * DIM_;
    const float* xmc = xm + (size_t)r0 * DIM_;
    float* outc = out_x + (size_t)r0 * DIM_;
    gemm_mfma<<<dim3(MLP_ / 128, (rows + 127) / 128), 256, 0, stream>>>(
        h2c, w1b, bfc1, nullptr, nullptr, gbc, rows, MLP_, DIM_, 1);
    gemm_mfma<<<dim3(DIM_ / 128, (rows + 127) / 128), 256, 0, stream>>>(
        gbc, w2b, bfc2, xmc, outc, nullptr, rows, DIM_, MLP_, 0);
    r0 += rows;
  }
}

// Round 6
// 666.618 us; speedup vs baseline: 7.8587x; 1.1910x over previous
//
#include <hip/hip_runtime.h>
#include <cstdint>
#include <cstddef>

#define DEVFN __device__ __forceinline__

typedef __attribute__((ext_vector_type(8))) short short8;
typedef __attribute__((ext_vector_type(4))) float f32x4;

// async global->LDS, 16B per lane; LDS dest = wave-uniform base + lane*16
#define GLOAD_LDS16(gaddr, laddr)                                              \
  __builtin_amdgcn_global_load_lds(                                            \
      (const __attribute__((address_space(1))) uint32_t*)(gaddr),              \
      (__attribute__((address_space(3))) uint32_t*)(laddr), 16, 0, 0)

// Problem constants
constexpr int B_ = 64, T_ = 197, DIM_ = 768, H_ = 12, HD_ = 64, MLP_ = 3072;
constexpr int N_ = B_ * T_;          // 12608 tokens
constexpr int NE_ = 99, NO_ = 98, REFF_ = 16;
constexpr int TM_ = (NE_ - REFF_) + NO_;  // 181 merged tokens
constexpr int NM_ = B_ * TM_;        // 11584 merged rows

// ---------------- workspace layout (BYTE offsets; all 16B-aligned) ----------------
// A [0, 58.1M): h fp32 -> qkvb bf16 -> x1 fp32 -> gbc bf16 (gbc spills into B)
// B [58.1M, 77.5M): hb bf16 -> ob bf16
// C [77.5M, 113.0M): xm fp32
// D [113.0M, 130.8M): met fp32 (3.2M) then overlaid by h2b bf16 (17.8M)
// tail: wkm, route, nsz, bf16 weights.  Total 146,075,392 B (< 159.2MB proven safe)
constexpr size_t BOFF_A    = 0;
constexpr size_t BOFF_GBC  = 0;            // 71,172,096 B, overlays A + part of B
constexpr size_t BOFF_B    = 58097664;
constexpr size_t BOFF_C    = 77463552;
constexpr size_t BOFF_D    = 113049600;    // met fp32 AND h2b bf16 (disjoint lifetimes)
constexpr size_t BOFF_WKM  = 130842624;
constexpr size_t BOFF_RT   = 131039232;
constexpr size_t BOFF_NSZ  = 131873280;
constexpr size_t BOFF_WQB  = 131919616;
constexpr size_t BOFF_WPB  = 135458560;
constexpr size_t BOFF_W1B  = 136638208;
constexpr size_t BOFF_W2B  = 141356800;

// ---------------- bf16 helpers ----------------
DEVFN ushort f2b(float f) {
  union { float f; uint u; } c; c.f = f;
  uint u = c.u;
  u = (u + 0x7FFFu + ((u >> 16) & 1u)) >> 16;
  return (ushort)u;
}
DEVFN float b2f(ushort h) {
  union { uint u; float f; } c; c.u = ((uint)h) << 16;
  return c.f;
}

// ---------------- reductions ----------------
DEVFN float wave_sum(float v) {
#pragma unroll
  for (int o = 32; o; o >>= 1) v += __shfl_down(v, o, 64);
  return v;
}
DEVFN float block_sum(float v, float* red) {
  v = wave_sum(v);
  int lane = threadIdx.x & 63, wid = threadIdx.x >> 6;
  __syncthreads();
  if (lane == 0) red[wid] = v;
  __syncthreads();
  return red[0] + red[1] + red[2] + red[3];
}

// ---------------- fp32 -> bf16 convert ----------------
__global__ __launch_bounds__(256) void f2b4_kernel(const float* __restrict__ src,
                                                   ushort* __restrict__ dst, int n) {
  int i = (blockIdx.x * 256 + threadIdx.x) * 4;
  if (i >= n) return;
  float4 v = *reinterpret_cast<const float4*>(src + i);
  ushort4 o;
  o.x = f2b(v.x); o.y = f2b(v.y); o.z = f2b(v.z); o.w = f2b(v.w);
  *reinterpret_cast<ushort4*>(dst + i) = o;
}

// ---------------- LayerNorm: optional fp32 + bf16 outputs ----------------
__global__ __launch_bounds__(256) void ln_kernel(
    const float* __restrict__ x, const float* __restrict__ g,
    const float* __restrict__ bb, float* __restrict__ outf,
    ushort* __restrict__ outb) {
  __shared__ float red[4];
  size_t row = blockIdx.x;
  const float* xr = x + row * DIM_;
  int tid = threadIdx.x;
  float s = 0.f;
  for (int i = tid; i < DIM_; i += 256) s += xr[i];
  s = block_sum(s, red);
  float mean = s * (1.0f / DIM_);
  float vs = 0.f;
  for (int i = tid; i < DIM_; i += 256) { float d = xr[i] - mean; vs = fmaf(d, d, vs); }
  vs = block_sum(vs, red);
  float rstd = rsqrtf(vs * (1.0f / DIM_) + 1e-5f);
  for (int i = tid; i < DIM_; i += 256) {
    float v = (xr[i] - mean) * rstd * g[i] + bb[i];
    if (outf) outf[row * DIM_ + i] = v;
    if (outb) outb[row * DIM_ + i] = f2b(v);
  }
}

// ---------------- head-averaged K weights ----------------
__global__ __launch_bounds__(256) void wkmean_kernel(const float* __restrict__ wqkv,
                                                     float* __restrict__ wkm) {
  int idx = blockIdx.x * 256 + threadIdx.x;
  if (idx >= HD_ * DIM_) return;
  int d = idx / DIM_, c = idx % DIM_;
  float s = 0.f;
  for (int h2 = 0; h2 < H_; h2++) s += wqkv[(size_t)(DIM_ + h2 * HD_ + d) * DIM_ + c];
  wkm[idx] = s * (1.0f / H_);
}

// ---------------- fp32 GEMM (kept for the index-deciding metric path) ----------------
__global__ __launch_bounds__(256) void gemm_bt(
    const float* __restrict__ A, const float* __restrict__ Bm,
    float* __restrict__ C, int M, int Nn, int K) {
  __shared__ float As[16][65];
  __shared__ float Bs[16][65];
  const int tid = threadIdx.x;
  const int tx = tid & 15, ty = tid >> 4;
  const int m0 = blockIdx.y * 64, n0 = blockIdx.x * 64;
  float acc[4][4] = {};
  for (int k0 = 0; k0 < K; k0 += 16) {
#pragma unroll
    for (int l = 0; l < 4; ++l) {
      int idx = tid + l * 256;
      int mm = idx >> 4, kk = idx & 15;
      As[kk][mm] = A[(size_t)(m0 + mm) * K + (k0 + kk)];
      Bs[kk][mm] = Bm[(size_t)(n0 + mm) * K + (k0 + kk)];
    }
    __syncthreads();
#pragma unroll
    for (int kk = 0; kk < 16; ++kk) {
      float av[4], bv[4];
#pragma unroll
      for (int i = 0; i < 4; i++) av[i] = As[kk][ty * 4 + i];
#pragma unroll
      for (int j = 0; j < 4; j++) bv[j] = Bs[kk][tx * 4 + j];
#pragma unroll
      for (int i = 0; i < 4; i++)
#pragma unroll
        for (int j = 0; j < 4; j++) acc[i][j] = fmaf(av[i], bv[j], acc[i][j]);
    }
    __syncthreads();
  }
#pragma unroll
  for (int i = 0; i < 4; i++) {
    size_t base = (size_t)(m0 + ty * 4 + i) * Nn + n0 + tx * 4;
#pragma unroll
    for (int j = 0; j < 4; j++) C[base + j] = acc[i][j];
  }
}

// ---------------- bf16 MFMA GEMM (m97 structure: global_load_lds, linear LDS) --------
// A: [M,K] bf16 row-major; Bw: [Nn,K] bf16 row-major. Nn%128==0, K%32==0; M arbitrary.
// Tile 128x128, BK=32, 4 waves in 2x2, each wave 64x64 = 4x4 frags of 16x16x32.
__global__ __launch_bounds__(256) void gemm_mfma(
    const ushort* __restrict__ A, const ushort* __restrict__ Bw,
    const float* __restrict__ bias, const float* __restrict__ res,
    float* __restrict__ Cf, ushort* __restrict__ Cb,
    int M, int Nn, int K, int act) {
  __shared__ ushort As[128][32];  // linear: global_load_lds needs contiguous lane order
  __shared__ ushort Bs[128][32];
  const int t = threadIdx.x;
  const int wid = t >> 6, l = t & 63;
  const int wrow = wid >> 1, wcol = wid & 1;
  const int lr = l & 15, lk = l >> 4;
  const int m0 = blockIdx.y * 128, n0 = blockIdx.x * 128;
  const int lrow = l >> 2, lseg = l & 3;  // lane's row/seg within a 16-row chunk

  f32x4 acc[4][4];
#pragma unroll
  for (int i = 0; i < 4; i++)
#pragma unroll
    for (int j = 0; j < 4; j++) acc[i][j] = (f32x4){0.f, 0.f, 0.f, 0.f};

  for (int k0 = 0; k0 < K; k0 += 32) {
    // wave wid stages A/B rows [wid*32, wid*32+32) via 2 issues of 16 rows each
#pragma unroll
    for (int i = 0; i < 2; i++) {
      int rchunk = wid * 32 + i * 16;
      int rowA = m0 + rchunk + lrow;
      rowA = rowA < M ? rowA : M - 1;
      GLOAD_LDS16(A + (size_t)rowA * K + k0 + lseg * 8, &As[rchunk][0]);
      int rowB = n0 + rchunk + lrow;
      GLOAD_LDS16(Bw + (size_t)rowB * K + k0 + lseg * 8, &Bs[rchunk][0]);
    }
    __syncthreads();
    short8 af[4], bf[4];
#pragma unroll
    for (int mi = 0; mi < 4; mi++)
      af[mi] = *reinterpret_cast<const short8*>(&As[wrow * 64 + mi * 16 + lr][lk * 8]);
#pragma unroll
    for (int nj = 0; nj < 4; nj++)
      bf[nj] = *reinterpret_cast<const short8*>(&Bs[wcol * 64 + nj * 16 + lr][lk * 8]);
#pragma unroll
    for (int mi = 0; mi < 4; mi++)
#pragma unroll
      for (int nj = 0; nj < 4; nj++)
        acc[mi][nj] = __builtin_amdgcn_mfma_f32_16x16x32_bf16(af[mi], bf[nj], acc[mi][nj], 0, 0, 0);
    __syncthreads();
  }

  // epilogue: C/D layout col=lane&15, row=(lane>>4)*4+j
#pragma unroll
  for (int mi = 0; mi < 4; mi++) {
    int rbase = m0 + wrow * 64 + mi * 16 + lk * 4;
#pragma unroll
    for (int nj = 0; nj < 4; nj++) {
      int col = n0 + wcol * 64 + nj * 16 + lr;
      float bv = bias ? bias[col] : 0.f;
#pragma unroll
      for (int j = 0; j < 4; j++) {
        int row = rbase + j;
        if (row >= M) continue;
        float v = acc[mi][nj][j] + bv;
        if (act) v = 0.5f * v * (1.0f + erff(v * 0.70710678118654752440f));
        size_t idx = (size_t)row * Nn + col;
        if (res) v += res[idx];
        if (Cf) Cf[idx] = v;
        else Cb[idx] = f2b(v);
      }
    }
  }
}

// ---------------- attention v3: MFMA flash-style, one block per (b,h) ----------------
__global__ __launch_bounds__(512) void attn3_kernel(
    const ushort* __restrict__ qkv, const float* __restrict__ asize,
    ushort* __restrict__ o) {
  __shared__ ushort Kb[208][72];       // 144B stride
  __shared__ ushort Vt[64][232];       // 464B stride; V transposed
  __shared__ ushort Plds[8][16][232];  // per-wave P strip
  __shared__ float lb[200];
  const int bh = blockIdx.x;
  const int h = bh % H_, b = bh / H_;
  const size_t bT = (size_t)b * T_;
  const int tid = threadIdx.x;
  const int l = tid & 63, wid = tid >> 6;
  const int lr = l & 15, lk = l >> 4;

  for (int j = tid; j < T_; j += 512) lb[j] = logf(asize[bT + j]);
  for (int idx = tid; idx < 208 * 8; idx += 512) {
    int row = idx >> 3, seg = idx & 7;
    int kr = row < T_ ? row : T_ - 1;
    *reinterpret_cast<uint4*>(&Kb[row][seg * 8]) = *reinterpret_cast<const uint4*>(
        qkv + (bT + kr) * (3 * DIM_) + DIM_ + h * HD_ + seg * 8);
  }
  for (int idx = tid; idx < 197 * 8; idx += 512) {
    int row = idx >> 3, seg = idx & 7;
    uint4 v = *reinterpret_cast<const uint4*>(
        qkv + (bT + row) * (3 * DIM_) + 2 * DIM_ + h * HD_ + seg * 8);
    const ushort* us = reinterpret_cast<const ushort*>(&v);
#pragma unroll
    for (int e = 0; e < 8; e++) Vt[seg * 8 + e][row] = us[e];
  }
  for (int idx = tid; idx < 64 * 35; idx += 512) Vt[idx / 35][197 + idx % 35] = 0;
  for (int i = tid; i < 8 * 16 * 116; i += 512) reinterpret_cast<uint*>(Plds)[i] = 0;
  __syncthreads();

  for (int s = wid; s < 13; s += 8) {
    const int q0 = s * 16;
    int qr = q0 + lr; qr = qr < T_ ? qr : T_ - 1;
    const ushort* qp = qkv + (bT + qr) * (3 * DIM_) + h * HD_;
    short8 aq0 = *reinterpret_cast<const short8*>(qp + lk * 8);
    short8 aq1 = *reinterpret_cast<const short8*>(qp + 32 + lk * 8);

    f32x4 accs[13];
#pragma unroll
    for (int t2 = 0; t2 < 13; t2++) accs[t2] = (f32x4){0.f, 0.f, 0.f, 0.f};
#pragma unroll
    for (int t2 = 0; t2 < 13; t2++) {
      short8 bk0 = *reinterpret_cast<const short8*>(&Kb[t2 * 16 + lr][lk * 8]);
      short8 bk1 = *reinterpret_cast<const short8*>(&Kb[t2 * 16 + lr][32 + lk * 8]);
      accs[t2] = __builtin_amdgcn_mfma_f32_16x16x32_bf16(aq0, bk0, accs[t2], 0, 0, 0);
      accs[t2] = __builtin_amdgcn_mfma_f32_16x16x32_bf16(aq1, bk1, accs[t2], 0, 0, 0);
    }
    const int col0 = lr;
    float m4[4] = {-INFINITY, -INFINITY, -INFINITY, -INFINITY};
#pragma unroll
    for (int t2 = 0; t2 < 13; t2++) {
      int col = t2 * 16 + col0;
      bool valid = col < T_;
      float lbv = valid ? lb[col] : 0.f;
#pragma unroll
      for (int j = 0; j < 4; j++) {
        float v = valid ? fmaf(accs[t2][j], 0.125f, lbv) : -INFINITY;
        accs[t2][j] = v;
        m4[j] = fmaxf(m4[j], v);
      }
    }
#pragma unroll
    for (int off = 1; off < 16; off <<= 1)
#pragma unroll
      for (int j = 0; j < 4; j++) m4[j] = fmaxf(m4[j], __shfl_xor(m4[j], off, 64));
    float s4[4] = {0.f, 0.f, 0.f, 0.f};
#pragma unroll
    for (int t2 = 0; t2 < 13; t2++)
#pragma unroll
      for (int j = 0; j < 4; j++) {
        float e = __expf(accs[t2][j] - m4[j]);
        accs[t2][j] = e;
        s4[j] += e;
      }
#pragma unroll
    for (int off = 1; off < 16; off <<= 1)
#pragma unroll
      for (int j = 0; j < 4; j++) s4[j] += __shfl_xor(s4[j], off, 64);
    float inv4[4];
#pragma unroll
    for (int j = 0; j < 4; j++) inv4[j] = 1.0f / s4[j];
#pragma unroll
    for (int t2 = 0; t2 < 13; t2++)
#pragma unroll
      for (int j = 0; j < 4; j++)
        Plds[wid][lk * 4 + j][t2 * 16 + col0] = f2b(accs[t2][j] * inv4[j]);

    f32x4 acco[4];
#pragma unroll
    for (int ct = 0; ct < 4; ct++) acco[ct] = (f32x4){0.f, 0.f, 0.f, 0.f};
#pragma unroll
    for (int kt = 0; kt < 7; kt++) {
      short8 ap = *reinterpret_cast<const short8*>(&Plds[wid][lr][kt * 32 + lk * 8]);
#pragma unroll
      for (int ct = 0; ct < 4; ct++) {
        short8 bv = *reinterpret_cast<const short8*>(&Vt[ct * 16 + lr][kt * 32 + lk * 8]);
        acco[ct] = __builtin_amdgcn_mfma_f32_16x16x32_bf16(ap, bv, acco[ct], 0, 0, 0);
      }
    }
#pragma unroll
    for (int ct = 0; ct < 4; ct++)
#pragma unroll
      for (int j = 0; j < 4; j++) {
        int row = q0 + lk * 4 + j;
        if (row < T_)
          o[(bT + row) * DIM_ + h * HD_ + ct * 16 + lr] = f2b(acco[ct][j]);
      }
  }
}

// ---------------- ToMe matching (fp32, decision-critical) ----------------
__global__ __launch_bounds__(256) void match_kernel(
    const float* __restrict__ metric, const float* __restrict__ asize,
    int* __restrict__ route, float* __restrict__ nsz,
    float* __restrict__ out_ns, float* __restrict__ out_rci) {
  __shared__ float m[197][65];
  __shared__ float nmax[99];
  __shared__ int nidx[99];
  __shared__ int rnk[99];
  __shared__ int srcr[16];
  __shared__ int dstr[16];
  __shared__ int unmp[99];
  int b = blockIdx.x;
  int tid = threadIdx.x;
  int lane = tid & 63, wid = tid >> 6;

  if (tid < T_) {
    const float* mr = metric + ((size_t)b * T_ + tid) * HD_;
    float ss = 0.f;
#pragma unroll
    for (int d = 0; d < 64; d++) { float v = mr[d]; ss = fmaf(v, v, ss); }
    float nrm = sqrtf(ss);
#pragma unroll
    for (int d = 0; d < 64; d++) m[tid][d] = mr[d] / nrm;
  }
  __syncthreads();

  for (int i = wid; i < NE_; i += 4) {
    if (i == 0) {
      if (lane == 0) { nmax[0] = -INFINITY; nidx[0] = 0; }
      continue;
    }
    float bv = -INFINITY;
    int bj = 1 << 30;
    for (int j = lane; j < NO_; j += 64) {
      const float* a = m[2 * i];
      const float* bb = m[2 * j + 1];
      float sdot = 0.f;
#pragma unroll
      for (int d = 0; d < 64; d++) sdot = fmaf(a[d], bb[d], sdot);
      if (sdot > bv) { bv = sdot; bj = j; }
    }
#pragma unroll
    for (int off = 32; off; off >>= 1) {
      float ov = __shfl_down(bv, off, 64);
      int oj = __shfl_down(bj, off, 64);
      if (ov > bv || (ov == bv && oj < bj)) { bv = ov; bj = oj; }
    }
    if (lane == 0) { nmax[i] = bv; nidx[i] = bj; }
  }
  __syncthreads();

  if (tid < NE_) {
    float v = nmax[tid];
    int r = 0;
    for (int i2 = 0; i2 < NE_; i2++) {
      float v2 = nmax[i2];
      r += (v2 > v) || (v2 == v && i2 < tid);
    }
    rnk[tid] = r;
  }
  __syncthreads();
  if (tid < NE_ && rnk[tid] < REFF_) { srcr[rnk[tid]] = tid; dstr[rnk[tid]] = nidx[tid]; }
  __syncthreads();
  if (tid < NE_ && rnk[tid] >= REFF_) {
    int p = 0;
    for (int i2 = 0; i2 < tid; i2++) p += (rnk[i2] >= REFF_);
    unmp[tid] = p;
    int* rr = route + ((size_t)b * TM_ + p) * 18;
    rr[0] = 1;
    rr[1] = 2 * tid;
  }
  if (tid < NO_) {
    int d = tid;
    int* rr = route + ((size_t)b * TM_ + (NE_ - REFF_) + d) * 18;
    int cnt = 1;
    rr[1] = 2 * d + 1;
    for (int r = 0; r < REFF_; r++)
      if (dstr[r] == d) { cnt++; rr[cnt] = 2 * srcr[r]; }
    rr[0] = cnt;
  }
  __syncthreads();

  for (int row = tid; row < TM_; row += 256) {
    const int* rr = route + ((size_t)b * TM_ + row) * 18;
    int cnt = rr[0];
    float s = 0.f;
    for (int t2 = 0; t2 < cnt; t2++) s += asize[(size_t)b * T_ + rr[1 + t2]];
    out_ns[(size_t)b * TM_ + row] = s;
    nsz[(size_t)b * TM_ + row] = s;
  }
  for (int t = 1 + tid; t < T_; t += 256) {
    int val;
    if (t & 1) {
      val = (NE_ - REFF_ - 1) + ((t - 1) >> 1);
    } else {
      int i = t >> 1;
      val = (rnk[i] >= REFF_) ? (unmp[i] - 1) : ((NE_ - REFF_ - 1) + nidx[i]);
    }
    out_rci[(size_t)b * (T_ - 1) + (t - 1)] = (float)val;
  }
}

// ---------------- merged x = merge(x1 * size) / new_size ----------------
__global__ __launch_bounds__(256) void merge_x_kernel(
    const float* __restrict__ x1, const float* __restrict__ asize,
    const int* __restrict__ route, const float* __restrict__ nsz,
    float* __restrict__ xm) {
  int row = blockIdx.x;
  int b = row / TM_;
  const int* rr = route + (size_t)row * 18;
  __shared__ int cnt_s;
  __shared__ int toks[17];
  __shared__ float szs[17];
  int tid = threadIdx.x;
  if (tid == 0) cnt_s = rr[0];
  __syncthreads();
  int cnt = cnt_s;
  if (tid < cnt) {
    int t = rr[1 + tid];
    toks[tid] = t;
    szs[tid] = asize[(size_t)b * T_ + t];
  }
  __syncthreads();
  float ns = nsz[row];
  for (int e = tid; e < DIM_; e += 256) {
    float acc = 0.f;
    for (int c2 = 0; c2 < cnt; c2++)
      acc = fmaf(x1[((size_t)b * T_ + toks[c2]) * DIM_ + e], szs[c2], acc);
    xm[(size_t)row * DIM_ + e] = acc / ns;
  }
}

// ---------------- launch ----------------
extern "C" void kernel_launch(void* const* d_in, const int* in_sizes, int n_in,
                              void* d_out, int out_size, void* d_ws, size_t ws_size,
                              hipStream_t stream) {
  const float* x_in = (const float*)d_in[0];
  const float* asize = (const float*)d_in[1];
  const float* ln1g = (const float*)d_in[2];
  const float* ln1b = (const float*)d_in[3];
  const float* wqkv = (const float*)d_in[4];
  const float* wproj = (const float*)d_in[5];
  const float* bproj = (const float*)d_in[6];
  const float* ln2g = (const float*)d_in[7];
  const float* ln2b = (const float*)d_in[8];
  const float* wfc1 = (const float*)d_in[9];
  const float* bfc1 = (const float*)d_in[10];
  const float* wfc2 = (const float*)d_in[11];
  const float* bfc2 = (const float*)d_in[12];

  char* base = (char*)d_ws;
  float* h    = (float*)(base + BOFF_A);
  ushort* qkvb = (ushort*)(base + BOFF_A);
  float* x1   = (float*)(base + BOFF_A);
  ushort* gbc = (ushort*)(base + BOFF_GBC);
  ushort* hb  = (ushort*)(base + BOFF_B);
  ushort* ob  = (ushort*)(base + BOFF_B);
  float* xm   = (float*)(base + BOFF_C);
  float* met  = (float*)(base + BOFF_D);
  ushort* h2b = (ushort*)(base + BOFF_D);  // overlays met (met dead before LN2)
  float* wkm  = (float*)(base + BOFF_WKM);
  int* route  = (int*)(base + BOFF_RT);
  float* nsz  = (float*)(base + BOFF_NSZ);
  ushort* wqb = (ushort*)(base + BOFF_WQB);
  ushort* wpb = (ushort*)(base + BOFF_WPB);
  ushort* w1b = (ushort*)(base + BOFF_W1B);
  ushort* w2b = (ushort*)(base + BOFF_W2B);

  float* out_x = (float*)d_out;
  float* out_ns = out_x + (size_t)NM_ * DIM_;
  float* out_rci = out_ns + NM_;

  f2b4_kernel<<<(3 * DIM_ * DIM_) / 1024, 256, 0, stream>>>(wqkv, wqb, 3 * DIM_ * DIM_);
  f2b4_kernel<<<(DIM_ * DIM_) / 1024, 256, 0, stream>>>(wproj, wpb, DIM_ * DIM_);
  f2b4_kernel<<<(MLP_ * DIM_) / 1024, 256, 0, stream>>>(wfc1, w1b, MLP_ * DIM_);
  f2b4_kernel<<<(DIM_ * MLP_) / 1024, 256, 0, stream>>>(wfc2, w2b, DIM_ * MLP_);
  wkmean_kernel<<<(HD_ * DIM_ + 255) / 256, 256, 0, stream>>>(wqkv, wkm);

  ln_kernel<<<N_, 256, 0, stream>>>(x_in, ln1g, ln1b, h, hb);
  gemm_bt<<<dim3(1, N_ / 64), 256, 0, stream>>>(h, wkm, met, N_, HD_, DIM_);
  gemm_mfma<<<dim3(3 * DIM_ / 128, (N_ + 127) / 128), 256, 0, stream>>>(
      hb, wqb, nullptr, nullptr, nullptr, qkvb, N_, 3 * DIM_, DIM_, 0);
  attn3_kernel<<<B_ * H_, 512, 0, stream>>>(qkvb, asize, ob);
  gemm_mfma<<<dim3(DIM_ / 128, (N_ + 127) / 128), 256, 0, stream>>>(
      ob, wpb, bproj, x_in, x1, nullptr, N_, DIM_, DIM_, 0);
  match_kernel<<<B_, 256, 0, stream>>>(met, asize, route, nsz, out_ns, out_rci);
  merge_x_kernel<<<NM_, 256, 0, stream>>>(x1, asize, route, nsz, xm);
  ln_kernel<<<NM_, 256, 0, stream>>>(xm, ln2g, ln2b, nullptr, h2b);

  // MLP unified (gbc sized for all NM_ rows): fc1 -> gelu -> bf16; fc2 + residual
  gemm_mfma<<<dim3(MLP_ / 128, (NM_ + 127) / 128), 256, 0, stream>>>(
      h2b, w1b, bfc1, nullptr, nullptr, gbc, NM_, MLP_, DIM_, 1);
  gemm_mfma<<<dim3(DIM_ / 128, (NM_ + 127) / 128), 256, 0, stream>>>(
      gbc, w2b, bfc2, xm, out_x, nullptr, NM_, DIM_, MLP_, 0);
}

// Round 7
// 612.036 us; speedup vs baseline: 8.5596x; 1.0892x over previous
//
#include <hip/hip_runtime.h>
#include <cstdint>
#include <cstddef>

#define DEVFN __device__ __forceinline__

typedef __attribute__((ext_vector_type(8))) short short8;
typedef __attribute__((ext_vector_type(4))) float f32x4;

// async global->LDS, 16B per lane; LDS dest = wave-uniform base + lane*16
#define GLOAD_LDS16(gaddr, laddr)                                              \
  __builtin_amdgcn_global_load_lds(                                            \
      (const __attribute__((address_space(1))) uint32_t*)(gaddr),              \
      (__attribute__((address_space(3))) uint32_t*)(laddr), 16, 0, 0)

// Problem constants
constexpr int B_ = 64, T_ = 197, DIM_ = 768, H_ = 12, HD_ = 64, MLP_ = 3072;
constexpr int N_ = B_ * T_;          // 12608 tokens
constexpr int NE_ = 99, NO_ = 98, REFF_ = 16;
constexpr int TM_ = (NE_ - REFF_) + NO_;  // 181 merged tokens
constexpr int NM_ = B_ * TM_;        // 11584 merged rows

// ---------------- workspace layout (BYTE offsets; all 16B-aligned) ----------------
// A [0, 58.1M): h fp32 -> qkvb bf16 -> x1 fp32 -> gbc bf16 (gbc spills into B)
// B [58.1M, 77.5M): hb bf16 -> ob bf16
// C [77.5M, 113.0M): xm fp32
// D [113.0M, 130.8M): met fp32 (3.2M) then overlaid by h2b bf16 (17.8M)
// tail: wkm, route, nsz, bf16 weights.  Total 146,075,392 B (< 159.2MB proven safe)
constexpr size_t BOFF_A    = 0;
constexpr size_t BOFF_GBC  = 0;            // 71,172,096 B, overlays A + part of B
constexpr size_t BOFF_B    = 58097664;
constexpr size_t BOFF_C    = 77463552;
constexpr size_t BOFF_D    = 113049600;    // met fp32 AND h2b bf16 (disjoint lifetimes)
constexpr size_t BOFF_WKM  = 130842624;
constexpr size_t BOFF_RT   = 131039232;
constexpr size_t BOFF_NSZ  = 131873280;
constexpr size_t BOFF_WQB  = 131919616;
constexpr size_t BOFF_WPB  = 135458560;
constexpr size_t BOFF_W1B  = 136638208;
constexpr size_t BOFF_W2B  = 141356800;

// ---------------- bf16 helpers ----------------
DEVFN ushort f2b(float f) {
  union { float f; uint u; } c; c.f = f;
  uint u = c.u;
  u = (u + 0x7FFFu + ((u >> 16) & 1u)) >> 16;
  return (ushort)u;
}
DEVFN float b2f(ushort h) {
  union { uint u; float f; } c; c.u = ((uint)h) << 16;
  return c.f;
}

// ---------------- reductions ----------------
DEVFN float wave_sum(float v) {
#pragma unroll
  for (int o = 32; o; o >>= 1) v += __shfl_down(v, o, 64);
  return v;
}
DEVFN float block_sum(float v, float* red) {
  v = wave_sum(v);
  int lane = threadIdx.x & 63, wid = threadIdx.x >> 6;
  __syncthreads();
  if (lane == 0) red[wid] = v;
  __syncthreads();
  return red[0] + red[1] + red[2] + red[3];
}

// ---------------- fp32 -> bf16 convert ----------------
__global__ __launch_bounds__(256) void f2b4_kernel(const float* __restrict__ src,
                                                   ushort* __restrict__ dst, int n) {
  int i = (blockIdx.x * 256 + threadIdx.x) * 4;
  if (i >= n) return;
  float4 v = *reinterpret_cast<const float4*>(src + i);
  ushort4 o;
  o.x = f2b(v.x); o.y = f2b(v.y); o.z = f2b(v.z); o.w = f2b(v.w);
  *reinterpret_cast<ushort4*>(dst + i) = o;
}

// ---------------- LayerNorm: optional fp32 + bf16 outputs ----------------
__global__ __launch_bounds__(256) void ln_kernel(
    const float* __restrict__ x, const float* __restrict__ g,
    const float* __restrict__ bb, float* __restrict__ outf,
    ushort* __restrict__ outb) {
  __shared__ float red[4];
  size_t row = blockIdx.x;
  const float* xr = x + row * DIM_;
  int tid = threadIdx.x;
  float s = 0.f;
  for (int i = tid; i < DIM_; i += 256) s += xr[i];
  s = block_sum(s, red);
  float mean = s * (1.0f / DIM_);
  float vs = 0.f;
  for (int i = tid; i < DIM_; i += 256) { float d = xr[i] - mean; vs = fmaf(d, d, vs); }
  vs = block_sum(vs, red);
  float rstd = rsqrtf(vs * (1.0f / DIM_) + 1e-5f);
  for (int i = tid; i < DIM_; i += 256) {
    float v = (xr[i] - mean) * rstd * g[i] + bb[i];
    if (outf) outf[row * DIM_ + i] = v;
    if (outb) outb[row * DIM_ + i] = f2b(v);
  }
}

// ---------------- head-averaged K weights ----------------
__global__ __launch_bounds__(256) void wkmean_kernel(const float* __restrict__ wqkv,
                                                     float* __restrict__ wkm) {
  int idx = blockIdx.x * 256 + threadIdx.x;
  if (idx >= HD_ * DIM_) return;
  int d = idx / DIM_, c = idx % DIM_;
  float s = 0.f;
  for (int h2 = 0; h2 < H_; h2++) s += wqkv[(size_t)(DIM_ + h2 * HD_ + d) * DIM_ + c];
  wkm[idx] = s * (1.0f / H_);
}

// ---------------- fp32 GEMM (kept for the index-deciding metric path) ----------------
__global__ __launch_bounds__(256) void gemm_bt(
    const float* __restrict__ A, const float* __restrict__ Bm,
    float* __restrict__ C, int M, int Nn, int K) {
  __shared__ float As[16][65];
  __shared__ float Bs[16][65];
  const int tid = threadIdx.x;
  const int tx = tid & 15, ty = tid >> 4;
  const int m0 = blockIdx.y * 64, n0 = blockIdx.x * 64;
  float acc[4][4] = {};
  for (int k0 = 0; k0 < K; k0 += 16) {
#pragma unroll
    for (int l = 0; l < 4; ++l) {
      int idx = tid + l * 256;
      int mm = idx >> 4, kk = idx & 15;
      As[kk][mm] = A[(size_t)(m0 + mm) * K + (k0 + kk)];
      Bs[kk][mm] = Bm[(size_t)(n0 + mm) * K + (k0 + kk)];
    }
    __syncthreads();
#pragma unroll
    for (int kk = 0; kk < 16; ++kk) {
      float av[4], bv[4];
#pragma unroll
      for (int i = 0; i < 4; i++) av[i] = As[kk][ty * 4 + i];
#pragma unroll
      for (int j = 0; j < 4; j++) bv[j] = Bs[kk][tx * 4 + j];
#pragma unroll
      for (int i = 0; i < 4; i++)
#pragma unroll
        for (int j = 0; j < 4; j++) acc[i][j] = fmaf(av[i], bv[j], acc[i][j]);
    }
    __syncthreads();
  }
#pragma unroll
  for (int i = 0; i < 4; i++) {
    size_t base = (size_t)(m0 + ty * 4 + i) * Nn + n0 + tx * 4;
#pragma unroll
    for (int j = 0; j < 4; j++) C[base + j] = acc[i][j];
  }
}

// ---------------- bf16 MFMA GEMM v2: 2-phase dbuf pipeline + XCD swizzle ----------
// A: [M,K] bf16 row-major; Bw: [Nn,K] bf16 row-major. Nn%128==0, K%32==0; M arbitrary.
// Tile 128x128, BK=32, 4 waves 2x2; 1D grid, bijective XCD swizzle (m204).
__global__ __launch_bounds__(256) void gemm_mfma(
    const ushort* __restrict__ A, const ushort* __restrict__ Bw,
    const float* __restrict__ bias, const float* __restrict__ res,
    float* __restrict__ Cf, ushort* __restrict__ Cb,
    int M, int Nn, int K, int act) {
  __shared__ ushort As[2][128][32];
  __shared__ ushort Bs[2][128][32];
  const int t = threadIdx.x;
  const int wid = t >> 6, l = t & 63;
  const int wrow = wid >> 1, wcol = wid & 1;
  const int lr = l & 15, lk = l >> 4;
  const int lrow = l >> 2, lseg = l & 3;

  // XCD-aware bijective remap: consecutive wgids (sharing an A-panel) -> same XCD L2
  const int nwg = (int)gridDim.x;
  const int gx = Nn >> 7;
  const int bid = (int)blockIdx.x;
  const int q = nwg >> 3, r = nwg & 7;
  const int xcd = bid & 7, sub = bid >> 3;
  const int wgid = (xcd < r ? xcd * (q + 1) : r * (q + 1) + (xcd - r) * q) + sub;
  const int m0 = (wgid / gx) * 128, n0 = (wgid % gx) * 128;

  f32x4 acc[4][4];
#pragma unroll
  for (int i = 0; i < 4; i++)
#pragma unroll
    for (int j = 0; j < 4; j++) acc[i][j] = (f32x4){0.f, 0.f, 0.f, 0.f};

  auto STAGE = [&](int buf, int kt) {
    const int k0 = kt * 32;
#pragma unroll
    for (int i = 0; i < 2; i++) {
      int rchunk = wid * 32 + i * 16;
      int rowA = m0 + rchunk + lrow;
      rowA = rowA < M ? rowA : M - 1;
      GLOAD_LDS16(A + (size_t)rowA * K + k0 + lseg * 8, &As[buf][rchunk][0]);
      int rowB = n0 + rchunk + lrow;
      GLOAD_LDS16(Bw + (size_t)rowB * K + k0 + lseg * 8, &Bs[buf][rchunk][0]);
    }
  };

  const int NT = K >> 5;
  STAGE(0, 0);
  asm volatile("s_waitcnt vmcnt(0)" ::: "memory");
  __builtin_amdgcn_s_barrier();

  int cur = 0;
  for (int kt = 0; kt < NT; kt++) {
    if (kt + 1 < NT) STAGE(cur ^ 1, kt + 1);   // issue next-tile loads early
    short8 af[4], bf[4];
#pragma unroll
    for (int mi = 0; mi < 4; mi++)
      af[mi] = *reinterpret_cast<const short8*>(&As[cur][wrow * 64 + mi * 16 + lr][lk * 8]);
#pragma unroll
    for (int nj = 0; nj < 4; nj++)
      bf[nj] = *reinterpret_cast<const short8*>(&Bs[cur][wcol * 64 + nj * 16 + lr][lk * 8]);
#pragma unroll
    for (int mi = 0; mi < 4; mi++)
#pragma unroll
      for (int nj = 0; nj < 4; nj++)
        acc[mi][nj] = __builtin_amdgcn_mfma_f32_16x16x32_bf16(af[mi], bf[nj], acc[mi][nj], 0, 0, 0);
    asm volatile("s_waitcnt vmcnt(0)" ::: "memory");  // prefetch landed (drained late)
    __builtin_amdgcn_s_barrier();
    cur ^= 1;
  }

  // epilogue: C/D layout col=lane&15, row=(lane>>4)*4+j
#pragma unroll
  for (int mi = 0; mi < 4; mi++) {
    int rbase = m0 + wrow * 64 + mi * 16 + lk * 4;
#pragma unroll
    for (int nj = 0; nj < 4; nj++) {
      int col = n0 + wcol * 64 + nj * 16 + lr;
      float bv = bias ? bias[col] : 0.f;
#pragma unroll
      for (int j = 0; j < 4; j++) {
        int row = rbase + j;
        if (row >= M) continue;
        float v = acc[mi][nj][j] + bv;
        if (act) v = 0.5f * v * (1.0f + erff(v * 0.70710678118654752440f));
        size_t idx = (size_t)row * Nn + col;
        if (res) v += res[idx];
        if (Cf) Cf[idx] = v;
        else Cb[idx] = f2b(v);
      }
    }
  }
}

// ---------------- attention v3: MFMA flash-style, one block per (b,h) ----------------
__global__ __launch_bounds__(512) void attn3_kernel(
    const ushort* __restrict__ qkv, const float* __restrict__ asize,
    ushort* __restrict__ o) {
  __shared__ ushort Kb[208][72];       // 144B stride
  __shared__ ushort Vt[64][232];       // 464B stride; V transposed
  __shared__ ushort Plds[8][16][232];  // per-wave P strip
  __shared__ float lb[200];
  const int bh = blockIdx.x;
  const int h = bh % H_, b = bh / H_;
  const size_t bT = (size_t)b * T_;
  const int tid = threadIdx.x;
  const int l = tid & 63, wid = tid >> 6;
  const int lr = l & 15, lk = l >> 4;

  for (int j = tid; j < T_; j += 512) lb[j] = logf(asize[bT + j]);
  for (int idx = tid; idx < 208 * 8; idx += 512) {
    int row = idx >> 3, seg = idx & 7;
    int kr = row < T_ ? row : T_ - 1;
    *reinterpret_cast<uint4*>(&Kb[row][seg * 8]) = *reinterpret_cast<const uint4*>(
        qkv + (bT + kr) * (3 * DIM_) + DIM_ + h * HD_ + seg * 8);
  }
  for (int idx = tid; idx < 197 * 8; idx += 512) {
    int row = idx >> 3, seg = idx & 7;
    uint4 v = *reinterpret_cast<const uint4*>(
        qkv + (bT + row) * (3 * DIM_) + 2 * DIM_ + h * HD_ + seg * 8);
    const ushort* us = reinterpret_cast<const ushort*>(&v);
#pragma unroll
    for (int e = 0; e < 8; e++) Vt[seg * 8 + e][row] = us[e];
  }
  for (int idx = tid; idx < 64 * 35; idx += 512) Vt[idx / 35][197 + idx % 35] = 0;
  for (int i = tid; i < 8 * 16 * 116; i += 512) reinterpret_cast<uint*>(Plds)[i] = 0;
  __syncthreads();

  for (int s = wid; s < 13; s += 8) {
    const int q0 = s * 16;
    int qr = q0 + lr; qr = qr < T_ ? qr : T_ - 1;
    const ushort* qp = qkv + (bT + qr) * (3 * DIM_) + h * HD_;
    short8 aq0 = *reinterpret_cast<const short8*>(qp + lk * 8);
    short8 aq1 = *reinterpret_cast<const short8*>(qp + 32 + lk * 8);

    f32x4 accs[13];
#pragma unroll
    for (int t2 = 0; t2 < 13; t2++) accs[t2] = (f32x4){0.f, 0.f, 0.f, 0.f};
#pragma unroll
    for (int t2 = 0; t2 < 13; t2++) {
      short8 bk0 = *reinterpret_cast<const short8*>(&Kb[t2 * 16 + lr][lk * 8]);
      short8 bk1 = *reinterpret_cast<const short8*>(&Kb[t2 * 16 + lr][32 + lk * 8]);
      accs[t2] = __builtin_amdgcn_mfma_f32_16x16x32_bf16(aq0, bk0, accs[t2], 0, 0, 0);
      accs[t2] = __builtin_amdgcn_mfma_f32_16x16x32_bf16(aq1, bk1, accs[t2], 0, 0, 0);
    }
    const int col0 = lr;
    float m4[4] = {-INFINITY, -INFINITY, -INFINITY, -INFINITY};
#pragma unroll
    for (int t2 = 0; t2 < 13; t2++) {
      int col = t2 * 16 + col0;
      bool valid = col < T_;
      float lbv = valid ? lb[col] : 0.f;
#pragma unroll
      for (int j = 0; j < 4; j++) {
        float v = valid ? fmaf(accs[t2][j], 0.125f, lbv) : -INFINITY;
        accs[t2][j] = v;
        m4[j] = fmaxf(m4[j], v);
      }
    }
#pragma unroll
    for (int off = 1; off < 16; off <<= 1)
#pragma unroll
      for (int j = 0; j < 4; j++) m4[j] = fmaxf(m4[j], __shfl_xor(m4[j], off, 64));
    float s4[4] = {0.f, 0.f, 0.f, 0.f};
#pragma unroll
    for (int t2 = 0; t2 < 13; t2++)
#pragma unroll
      for (int j = 0; j < 4; j++) {
        float e = __expf(accs[t2][j] - m4[j]);
        accs[t2][j] = e;
        s4[j] += e;
      }
#pragma unroll
    for (int off = 1; off < 16; off <<= 1)
#pragma unroll
      for (int j = 0; j < 4; j++) s4[j] += __shfl_xor(s4[j], off, 64);
    float inv4[4];
#pragma unroll
    for (int j = 0; j < 4; j++) inv4[j] = 1.0f / s4[j];
#pragma unroll
    for (int t2 = 0; t2 < 13; t2++)
#pragma unroll
      for (int j = 0; j < 4; j++)
        Plds[wid][lk * 4 + j][t2 * 16 + col0] = f2b(accs[t2][j] * inv4[j]);

    f32x4 acco[4];
#pragma unroll
    for (int ct = 0; ct < 4; ct++) acco[ct] = (f32x4){0.f, 0.f, 0.f, 0.f};
#pragma unroll
    for (int kt = 0; kt < 7; kt++) {
      short8 ap = *reinterpret_cast<const short8*>(&Plds[wid][lr][kt * 32 + lk * 8]);
#pragma unroll
      for (int ct = 0; ct < 4; ct++) {
        short8 bv = *reinterpret_cast<const short8*>(&Vt[ct * 16 + lr][kt * 32 + lk * 8]);
        acco[ct] = __builtin_amdgcn_mfma_f32_16x16x32_bf16(ap, bv, acco[ct], 0, 0, 0);
      }
    }
#pragma unroll
    for (int ct = 0; ct < 4; ct++)
#pragma unroll
      for (int j = 0; j < 4; j++) {
        int row = q0 + lk * 4 + j;
        if (row < T_)
          o[(bT + row) * DIM_ + h * HD_ + ct * 16 + lr] = f2b(acco[ct][j]);
      }
  }
}

// ---------------- ToMe matching (fp32, decision-critical) ----------------
__global__ __launch_bounds__(256) void match_kernel(
    const float* __restrict__ metric, const float* __restrict__ asize,
    int* __restrict__ route, float* __restrict__ nsz,
    float* __restrict__ out_ns, float* __restrict__ out_rci) {
  __shared__ float m[197][65];
  __shared__ float nmax[99];
  __shared__ int nidx[99];
  __shared__ int rnk[99];
  __shared__ int srcr[16];
  __shared__ int dstr[16];
  __shared__ int unmp[99];
  int b = blockIdx.x;
  int tid = threadIdx.x;
  int lane = tid & 63, wid = tid >> 6;

  if (tid < T_) {
    const float* mr = metric + ((size_t)b * T_ + tid) * HD_;
    float ss = 0.f;
#pragma unroll
    for (int d = 0; d < 64; d++) { float v = mr[d]; ss = fmaf(v, v, ss); }
    float nrm = sqrtf(ss);
#pragma unroll
    for (int d = 0; d < 64; d++) m[tid][d] = mr[d] / nrm;
  }
  __syncthreads();

  for (int i = wid; i < NE_; i += 4) {
    if (i == 0) {
      if (lane == 0) { nmax[0] = -INFINITY; nidx[0] = 0; }
      continue;
    }
    float bv = -INFINITY;
    int bj = 1 << 30;
    for (int j = lane; j < NO_; j += 64) {
      const float* a = m[2 * i];
      const float* bb = m[2 * j + 1];
      float sdot = 0.f;
#pragma unroll
      for (int d = 0; d < 64; d++) sdot = fmaf(a[d], bb[d], sdot);
      if (sdot > bv) { bv = sdot; bj = j; }
    }
#pragma unroll
    for (int off = 32; off; off >>= 1) {
      float ov = __shfl_down(bv, off, 64);
      int oj = __shfl_down(bj, off, 64);
      if (ov > bv || (ov == bv && oj < bj)) { bv = ov; bj = oj; }
    }
    if (lane == 0) { nmax[i] = bv; nidx[i] = bj; }
  }
  __syncthreads();

  if (tid < NE_) {
    float v = nmax[tid];
    int r = 0;
    for (int i2 = 0; i2 < NE_; i2++) {
      float v2 = nmax[i2];
      r += (v2 > v) || (v2 == v && i2 < tid);
    }
    rnk[tid] = r;
  }
  __syncthreads();
  if (tid < NE_ && rnk[tid] < REFF_) { srcr[rnk[tid]] = tid; dstr[rnk[tid]] = nidx[tid]; }
  __syncthreads();
  if (tid < NE_ && rnk[tid] >= REFF_) {
    int p = 0;
    for (int i2 = 0; i2 < tid; i2++) p += (rnk[i2] >= REFF_);
    unmp[tid] = p;
    int* rr = route + ((size_t)b * TM_ + p) * 18;
    rr[0] = 1;
    rr[1] = 2 * tid;
  }
  if (tid < NO_) {
    int d = tid;
    int* rr = route + ((size_t)b * TM_ + (NE_ - REFF_) + d) * 18;
    int cnt = 1;
    rr[1] = 2 * d + 1;
    for (int r = 0; r < REFF_; r++)
      if (dstr[r] == d) { cnt++; rr[cnt] = 2 * srcr[r]; }
    rr[0] = cnt;
  }
  __syncthreads();

  for (int row = tid; row < TM_; row += 256) {
    const int* rr = route + ((size_t)b * TM_ + row) * 18;
    int cnt = rr[0];
    float s = 0.f;
    for (int t2 = 0; t2 < cnt; t2++) s += asize[(size_t)b * T_ + rr[1 + t2]];
    out_ns[(size_t)b * TM_ + row] = s;
    nsz[(size_t)b * TM_ + row] = s;
  }
  for (int t = 1 + tid; t < T_; t += 256) {
    int val;
    if (t & 1) {
      val = (NE_ - REFF_ - 1) + ((t - 1) >> 1);
    } else {
      int i = t >> 1;
      val = (rnk[i] >= REFF_) ? (unmp[i] - 1) : ((NE_ - REFF_ - 1) + nidx[i]);
    }
    out_rci[(size_t)b * (T_ - 1) + (t - 1)] = (float)val;
  }
}

// ---------------- merged x = merge(x1 * size) / new_size ----------------
__global__ __launch_bounds__(256) void merge_x_kernel(
    const float* __restrict__ x1, const float* __restrict__ asize,
    const int* __restrict__ route, const float* __restrict__ nsz,
    float* __restrict__ xm) {
  int row = blockIdx.x;
  int b = row / TM_;
  const int* rr = route + (size_t)row * 18;
  __shared__ int cnt_s;
  __shared__ int toks[17];
  __shared__ float szs[17];
  int tid = threadIdx.x;
  if (tid == 0) cnt_s = rr[0];
  __syncthreads();
  int cnt = cnt_s;
  if (tid < cnt) {
    int t = rr[1 + tid];
    toks[tid] = t;
    szs[tid] = asize[(size_t)b * T_ + t];
  }
  __syncthreads();
  float ns = nsz[row];
  for (int e = tid; e < DIM_; e += 256) {
    float acc = 0.f;
    for (int c2 = 0; c2 < cnt; c2++)
      acc = fmaf(x1[((size_t)b * T_ + toks[c2]) * DIM_ + e], szs[c2], acc);
    xm[(size_t)row * DIM_ + e] = acc / ns;
  }
}

// ---------------- launch ----------------
extern "C" void kernel_launch(void* const* d_in, const int* in_sizes, int n_in,
                              void* d_out, int out_size, void* d_ws, size_t ws_size,
                              hipStream_t stream) {
  const float* x_in = (const float*)d_in[0];
  const float* asize = (const float*)d_in[1];
  const float* ln1g = (const float*)d_in[2];
  const float* ln1b = (const float*)d_in[3];
  const float* wqkv = (const float*)d_in[4];
  const float* wproj = (const float*)d_in[5];
  const float* bproj = (const float*)d_in[6];
  const float* ln2g = (const float*)d_in[7];
  const float* ln2b = (const float*)d_in[8];
  const float* wfc1 = (const float*)d_in[9];
  const float* bfc1 = (const float*)d_in[10];
  const float* wfc2 = (const float*)d_in[11];
  const float* bfc2 = (const float*)d_in[12];

  char* base = (char*)d_ws;
  float* h    = (float*)(base + BOFF_A);
  ushort* qkvb = (ushort*)(base + BOFF_A);
  float* x1   = (float*)(base + BOFF_A);
  ushort* gbc = (ushort*)(base + BOFF_GBC);
  ushort* hb  = (ushort*)(base + BOFF_B);
  ushort* ob  = (ushort*)(base + BOFF_B);
  float* xm   = (float*)(base + BOFF_C);
  float* met  = (float*)(base + BOFF_D);
  ushort* h2b = (ushort*)(base + BOFF_D);  // overlays met (met dead before LN2)
  float* wkm  = (float*)(base + BOFF_WKM);
  int* route  = (int*)(base + BOFF_RT);
  float* nsz  = (float*)(base + BOFF_NSZ);
  ushort* wqb = (ushort*)(base + BOFF_WQB);
  ushort* wpb = (ushort*)(base + BOFF_WPB);
  ushort* w1b = (ushort*)(base + BOFF_W1B);
  ushort* w2b = (ushort*)(base + BOFF_W2B);

  float* out_x = (float*)d_out;
  float* out_ns = out_x + (size_t)NM_ * DIM_;
  float* out_rci = out_ns + NM_;

  f2b4_kernel<<<(3 * DIM_ * DIM_) / 1024, 256, 0, stream>>>(wqkv, wqb, 3 * DIM_ * DIM_);
  f2b4_kernel<<<(DIM_ * DIM_) / 1024, 256, 0, stream>>>(wproj, wpb, DIM_ * DIM_);
  f2b4_kernel<<<(MLP_ * DIM_) / 1024, 256, 0, stream>>>(wfc1, w1b, MLP_ * DIM_);
  f2b4_kernel<<<(DIM_ * MLP_) / 1024, 256, 0, stream>>>(wfc2, w2b, DIM_ * MLP_);
  wkmean_kernel<<<(HD_ * DIM_ + 255) / 256, 256, 0, stream>>>(wqkv, wkm);

  ln_kernel<<<N_, 256, 0, stream>>>(x_in, ln1g, ln1b, h, hb);
  gemm_bt<<<dim3(1, N_ / 64), 256, 0, stream>>>(h, wkm, met, N_, HD_, DIM_);
  // 1D grids: gx*gy blocks, swizzled inside
  gemm_mfma<<<(3 * DIM_ / 128) * ((N_ + 127) / 128), 256, 0, stream>>>(
      hb, wqb, nullptr, nullptr, nullptr, qkvb, N_, 3 * DIM_, DIM_, 0);
  attn3_kernel<<<B_ * H_, 512, 0, stream>>>(qkvb, asize, ob);
  gemm_mfma<<<(DIM_ / 128) * ((N_ + 127) / 128), 256, 0, stream>>>(
      ob, wpb, bproj, x_in, x1, nullptr, N_, DIM_, DIM_, 0);
  match_kernel<<<B_, 256, 0, stream>>>(met, asize, route, nsz, out_ns, out_rci);
  merge_x_kernel<<<NM_, 256, 0, stream>>>(x1, asize, route, nsz, xm);
  ln_kernel<<<NM_, 256, 0, stream>>>(xm, ln2g, ln2b, nullptr, h2b);

  gemm_mfma<<<(MLP_ / 128) * ((NM_ + 127) / 128), 256, 0, stream>>>(
      h2b, w1b, bfc1, nullptr, nullptr, gbc, NM_, MLP_, DIM_, 1);
  gemm_mfma<<<(DIM_ / 128) * ((NM_ + 127) / 128), 256, 0, stream>>>(
      gbc, w2b, bfc2, xm, out_x, nullptr, NM_, DIM_, MLP_, 0);
}

// Round 8
// 607.968 us; speedup vs baseline: 8.6169x; 1.0067x over previous
//
#include <hip/hip_runtime.h>
#include <cstdint>
#include <cstddef>

#define DEVFN __device__ __forceinline__

typedef __attribute__((ext_vector_type(8))) short short8;
typedef __attribute__((ext_vector_type(4))) float f32x4;

// async global->LDS, 16B per lane; LDS dest = wave-uniform base + lane*16
#define GLOAD_LDS16(gaddr, laddr)                                              \
  __builtin_amdgcn_global_load_lds(                                            \
      (const __attribute__((address_space(1))) uint32_t*)(gaddr),              \
      (__attribute__((address_space(3))) uint32_t*)(laddr), 16, 0, 0)

// Problem constants
constexpr int B_ = 64, T_ = 197, DIM_ = 768, H_ = 12, HD_ = 64, MLP_ = 3072;
constexpr int N_ = B_ * T_;          // 12608 tokens
constexpr int NE_ = 99, NO_ = 98, REFF_ = 16;
constexpr int TM_ = (NE_ - REFF_) + NO_;  // 181 merged tokens
constexpr int NM_ = B_ * TM_;        // 11584 merged rows

// ---------------- workspace layout (BYTE offsets; all 16B-aligned) ----------------
constexpr size_t BOFF_A    = 0;
constexpr size_t BOFF_GBC  = 0;            // 71,172,096 B, overlays A + part of B
constexpr size_t BOFF_B    = 58097664;
constexpr size_t BOFF_C    = 77463552;
constexpr size_t BOFF_D    = 113049600;    // met fp32 AND h2b bf16 (disjoint lifetimes)
constexpr size_t BOFF_WKM  = 130842624;
constexpr size_t BOFF_RT   = 131039232;
constexpr size_t BOFF_NSZ  = 131873280;
constexpr size_t BOFF_WQB  = 131919616;
constexpr size_t BOFF_WPB  = 135458560;
constexpr size_t BOFF_W1B  = 136638208;
constexpr size_t BOFF_W2B  = 141356800;

// ---------------- bf16 helpers ----------------
DEVFN ushort f2b(float f) {
  union { float f; uint u; } c; c.f = f;
  uint u = c.u;
  u = (u + 0x7FFFu + ((u >> 16) & 1u)) >> 16;
  return (ushort)u;
}
DEVFN float b2f(ushort h) {
  union { uint u; float f; } c; c.u = ((uint)h) << 16;
  return c.f;
}

// ---------------- reductions ----------------
DEVFN float wave_sum(float v) {
#pragma unroll
  for (int o = 32; o; o >>= 1) v += __shfl_down(v, o, 64);
  return v;
}
DEVFN float block_sum(float v, float* red) {
  v = wave_sum(v);
  int lane = threadIdx.x & 63, wid = threadIdx.x >> 6;
  __syncthreads();
  if (lane == 0) red[wid] = v;
  __syncthreads();
  return red[0] + red[1] + red[2] + red[3];
}

// ---------------- fp32 -> bf16 convert ----------------
__global__ __launch_bounds__(256) void f2b4_kernel(const float* __restrict__ src,
                                                   ushort* __restrict__ dst, int n) {
  int i = (blockIdx.x * 256 + threadIdx.x) * 4;
  if (i >= n) return;
  float4 v = *reinterpret_cast<const float4*>(src + i);
  ushort4 o;
  o.x = f2b(v.x); o.y = f2b(v.y); o.z = f2b(v.z); o.w = f2b(v.w);
  *reinterpret_cast<ushort4*>(dst + i) = o;
}

// ---------------- LayerNorm: optional fp32 + bf16 outputs ----------------
__global__ __launch_bounds__(256) void ln_kernel(
    const float* __restrict__ x, const float* __restrict__ g,
    const float* __restrict__ bb, float* __restrict__ outf,
    ushort* __restrict__ outb) {
  __shared__ float red[4];
  size_t row = blockIdx.x;
  const float* xr = x + row * DIM_;
  int tid = threadIdx.x;
  float s = 0.f;
  for (int i = tid; i < DIM_; i += 256) s += xr[i];
  s = block_sum(s, red);
  float mean = s * (1.0f / DIM_);
  float vs = 0.f;
  for (int i = tid; i < DIM_; i += 256) { float d = xr[i] - mean; vs = fmaf(d, d, vs); }
  vs = block_sum(vs, red);
  float rstd = rsqrtf(vs * (1.0f / DIM_) + 1e-5f);
  for (int i = tid; i < DIM_; i += 256) {
    float v = (xr[i] - mean) * rstd * g[i] + bb[i];
    if (outf) outf[row * DIM_ + i] = v;
    if (outb) outb[row * DIM_ + i] = f2b(v);
  }
}

// ---------------- head-averaged K weights ----------------
__global__ __launch_bounds__(256) void wkmean_kernel(const float* __restrict__ wqkv,
                                                     float* __restrict__ wkm) {
  int idx = blockIdx.x * 256 + threadIdx.x;
  if (idx >= HD_ * DIM_) return;
  int d = idx / DIM_, c = idx % DIM_;
  float s = 0.f;
  for (int h2 = 0; h2 < H_; h2++) s += wqkv[(size_t)(DIM_ + h2 * HD_ + d) * DIM_ + c];
  wkm[idx] = s * (1.0f / H_);
}

// ---------------- fp32 GEMM (kept for the index-deciding metric path) ----------------
__global__ __launch_bounds__(256) void gemm_bt(
    const float* __restrict__ A, const float* __restrict__ Bm,
    float* __restrict__ C, int M, int Nn, int K) {
  __shared__ float As[16][65];
  __shared__ float Bs[16][65];
  const int tid = threadIdx.x;
  const int tx = tid & 15, ty = tid >> 4;
  const int m0 = blockIdx.y * 64, n0 = blockIdx.x * 64;
  float acc[4][4] = {};
  for (int k0 = 0; k0 < K; k0 += 16) {
#pragma unroll
    for (int l = 0; l < 4; ++l) {
      int idx = tid + l * 256;
      int mm = idx >> 4, kk = idx & 15;
      As[kk][mm] = A[(size_t)(m0 + mm) * K + (k0 + kk)];
      Bs[kk][mm] = Bm[(size_t)(n0 + mm) * K + (k0 + kk)];
    }
    __syncthreads();
#pragma unroll
    for (int kk = 0; kk < 16; ++kk) {
      float av[4], bv[4];
#pragma unroll
      for (int i = 0; i < 4; i++) av[i] = As[kk][ty * 4 + i];
#pragma unroll
      for (int j = 0; j < 4; j++) bv[j] = Bs[kk][tx * 4 + j];
#pragma unroll
      for (int i = 0; i < 4; i++)
#pragma unroll
        for (int j = 0; j < 4; j++) acc[i][j] = fmaf(av[i], bv[j], acc[i][j]);
    }
    __syncthreads();
  }
#pragma unroll
  for (int i = 0; i < 4; i++) {
    size_t base = (size_t)(m0 + ty * 4 + i) * Nn + n0 + tx * 4;
#pragma unroll
    for (int j = 0; j < 4; j++) C[base + j] = acc[i][j];
  }
}

// ---------------- bf16 MFMA GEMM v3: dbuf pipeline + XCD swizzle + T2 LDS swizzle ----
// A: [M,K] bf16 row-major; Bw: [Nn,K] bf16 row-major. Nn%128==0, K%32==0; M arbitrary.
// Tile 128x128, BK=32, 4 waves 2x2; 1D grid, bijective XCD swizzle (m204).
// LDS slot-swizzle (rule #21 both-sides): linear dest, pre-swizzled global source
// seg^=(row>>1)&3, same XOR on fragment reads -> 2-way (free) bank access.
__global__ __launch_bounds__(256) void gemm_mfma(
    const ushort* __restrict__ A, const ushort* __restrict__ Bw,
    const float* __restrict__ bias, const float* __restrict__ res,
    float* __restrict__ Cf, ushort* __restrict__ Cb,
    int M, int Nn, int K, int act) {
  __shared__ ushort As[2][128][32];
  __shared__ ushort Bs[2][128][32];
  const int t = threadIdx.x;
  const int wid = t >> 6, l = t & 63;
  const int wrow = wid >> 1, wcol = wid & 1;
  const int lr = l & 15, lk = l >> 4;
  const int lrow = l >> 2, lseg = l & 3;
  const int sswz = lseg ^ ((lrow >> 1) & 3);   // staging-side slot swizzle
  const int rswz = (lr >> 1) & 3;              // read-side slot swizzle (XOR with lk)

  // XCD-aware bijective remap: consecutive wgids (sharing an A-panel) -> same XCD L2
  const int nwg = (int)gridDim.x;
  const int gx = Nn >> 7;
  const int bid = (int)blockIdx.x;
  const int q = nwg >> 3, r = nwg & 7;
  const int xcd = bid & 7, sub = bid >> 3;
  const int wgid = (xcd < r ? xcd * (q + 1) : r * (q + 1) + (xcd - r) * q) + sub;
  const int m0 = (wgid / gx) * 128, n0 = (wgid % gx) * 128;

  f32x4 acc[4][4];
#pragma unroll
  for (int i = 0; i < 4; i++)
#pragma unroll
    for (int j = 0; j < 4; j++) acc[i][j] = (f32x4){0.f, 0.f, 0.f, 0.f};

  auto STAGE = [&](int buf, int kt) {
    const int k0 = kt * 32;
#pragma unroll
    for (int i = 0; i < 2; i++) {
      int rchunk = wid * 32 + i * 16;
      int rowA = m0 + rchunk + lrow;
      rowA = rowA < M ? rowA : M - 1;
      GLOAD_LDS16(A + (size_t)rowA * K + k0 + sswz * 8, &As[buf][rchunk][0]);
      int rowB = n0 + rchunk + lrow;
      GLOAD_LDS16(Bw + (size_t)rowB * K + k0 + sswz * 8, &Bs[buf][rchunk][0]);
    }
  };

  const int NT = K >> 5;
  STAGE(0, 0);
  asm volatile("s_waitcnt vmcnt(0)" ::: "memory");
  __builtin_amdgcn_s_barrier();

  int cur = 0;
  for (int kt = 0; kt < NT; kt++) {
    if (kt + 1 < NT) STAGE(cur ^ 1, kt + 1);   // issue next-tile loads early
    short8 af[4], bf[4];
#pragma unroll
    for (int mi = 0; mi < 4; mi++)
      af[mi] = *reinterpret_cast<const short8*>(
          &As[cur][wrow * 64 + mi * 16 + lr][(lk ^ rswz) * 8]);
#pragma unroll
    for (int nj = 0; nj < 4; nj++)
      bf[nj] = *reinterpret_cast<const short8*>(
          &Bs[cur][wcol * 64 + nj * 16 + lr][(lk ^ rswz) * 8]);
#pragma unroll
    for (int mi = 0; mi < 4; mi++)
#pragma unroll
      for (int nj = 0; nj < 4; nj++)
        acc[mi][nj] = __builtin_amdgcn_mfma_f32_16x16x32_bf16(af[mi], bf[nj], acc[mi][nj], 0, 0, 0);
    asm volatile("s_waitcnt vmcnt(0)" ::: "memory");  // prefetch landed (drained late)
    __builtin_amdgcn_s_barrier();
    cur ^= 1;
  }

  // epilogue: C/D layout col=lane&15, row=(lane>>4)*4+j
#pragma unroll
  for (int mi = 0; mi < 4; mi++) {
    int rbase = m0 + wrow * 64 + mi * 16 + lk * 4;
#pragma unroll
    for (int nj = 0; nj < 4; nj++) {
      int col = n0 + wcol * 64 + nj * 16 + lr;
      float bv = bias ? bias[col] : 0.f;
#pragma unroll
      for (int j = 0; j < 4; j++) {
        int row = rbase + j;
        if (row >= M) continue;
        float v = acc[mi][nj][j] + bv;
        if (act) v = 0.5f * v * (1.0f + erff(v * 0.70710678118654752440f));
        size_t idx = (size_t)row * Nn + col;
        if (res) v += res[idx];
        if (Cf) Cf[idx] = v;
        else Cb[idx] = f2b(v);
      }
    }
  }
}

// ---------------- attention v3: MFMA flash-style, one block per (b,h) ----------------
__global__ __launch_bounds__(512) void attn3_kernel(
    const ushort* __restrict__ qkv, const float* __restrict__ asize,
    ushort* __restrict__ o) {
  __shared__ ushort Kb[208][72];       // 144B stride -> 2-way (free)
  __shared__ ushort Vt[64][232];       // 464B stride; V transposed
  __shared__ ushort Plds[8][16][232];  // per-wave P strip
  __shared__ float lb[200];
  const int bh = blockIdx.x;
  const int h = bh % H_, b = bh / H_;
  const size_t bT = (size_t)b * T_;
  const int tid = threadIdx.x;
  const int l = tid & 63, wid = tid >> 6;
  const int lr = l & 15, lk = l >> 4;

  for (int j = tid; j < T_; j += 512) lb[j] = logf(asize[bT + j]);
  for (int idx = tid; idx < 208 * 8; idx += 512) {
    int row = idx >> 3, seg = idx & 7;
    int kr = row < T_ ? row : T_ - 1;
    *reinterpret_cast<uint4*>(&Kb[row][seg * 8]) = *reinterpret_cast<const uint4*>(
        qkv + (bT + kr) * (3 * DIM_) + DIM_ + h * HD_ + seg * 8);
  }
  for (int idx = tid; idx < 197 * 8; idx += 512) {
    int row = idx >> 3, seg = idx & 7;
    uint4 v = *reinterpret_cast<const uint4*>(
        qkv + (bT + row) * (3 * DIM_) + 2 * DIM_ + h * HD_ + seg * 8);
    const ushort* us = reinterpret_cast<const ushort*>(&v);
#pragma unroll
    for (int e = 0; e < 8; e++) Vt[seg * 8 + e][row] = us[e];
  }
  for (int idx = tid; idx < 64 * 35; idx += 512) Vt[idx / 35][197 + idx % 35] = 0;
  for (int i = tid; i < 8 * 16 * 116; i += 512) reinterpret_cast<uint*>(Plds)[i] = 0;
  __syncthreads();

  for (int s = wid; s < 13; s += 8) {
    const int q0 = s * 16;
    int qr = q0 + lr; qr = qr < T_ ? qr : T_ - 1;
    const ushort* qp = qkv + (bT + qr) * (3 * DIM_) + h * HD_;
    short8 aq0 = *reinterpret_cast<const short8*>(qp + lk * 8);
    short8 aq1 = *reinterpret_cast<const short8*>(qp + 32 + lk * 8);

    f32x4 accs[13];
#pragma unroll
    for (int t2 = 0; t2 < 13; t2++) accs[t2] = (f32x4){0.f, 0.f, 0.f, 0.f};
#pragma unroll
    for (int t2 = 0; t2 < 13; t2++) {
      short8 bk0 = *reinterpret_cast<const short8*>(&Kb[t2 * 16 + lr][lk * 8]);
      short8 bk1 = *reinterpret_cast<const short8*>(&Kb[t2 * 16 + lr][32 + lk * 8]);
      accs[t2] = __builtin_amdgcn_mfma_f32_16x16x32_bf16(aq0, bk0, accs[t2], 0, 0, 0);
      accs[t2] = __builtin_amdgcn_mfma_f32_16x16x32_bf16(aq1, bk1, accs[t2], 0, 0, 0);
    }
    const int col0 = lr;
    float m4[4] = {-INFINITY, -INFINITY, -INFINITY, -INFINITY};
#pragma unroll
    for (int t2 = 0; t2 < 13; t2++) {
      int col = t2 * 16 + col0;
      bool valid = col < T_;
      float lbv = valid ? lb[col] : 0.f;
#pragma unroll
      for (int j = 0; j < 4; j++) {
        float v = valid ? fmaf(accs[t2][j], 0.125f, lbv) : -INFINITY;
        accs[t2][j] = v;
        m4[j] = fmaxf(m4[j], v);
      }
    }
#pragma unroll
    for (int off = 1; off < 16; off <<= 1)
#pragma unroll
      for (int j = 0; j < 4; j++) m4[j] = fmaxf(m4[j], __shfl_xor(m4[j], off, 64));
    float s4[4] = {0.f, 0.f, 0.f, 0.f};
#pragma unroll
    for (int t2 = 0; t2 < 13; t2++)
#pragma unroll
      for (int j = 0; j < 4; j++) {
        float e = __expf(accs[t2][j] - m4[j]);
        accs[t2][j] = e;
        s4[j] += e;
      }
#pragma unroll
    for (int off = 1; off < 16; off <<= 1)
#pragma unroll
      for (int j = 0; j < 4; j++) s4[j] += __shfl_xor(s4[j], off, 64);
    float inv4[4];
#pragma unroll
    for (int j = 0; j < 4; j++) inv4[j] = 1.0f / s4[j];
#pragma unroll
    for (int t2 = 0; t2 < 13; t2++)
#pragma unroll
      for (int j = 0; j < 4; j++)
        Plds[wid][lk * 4 + j][t2 * 16 + col0] = f2b(accs[t2][j] * inv4[j]);

    f32x4 acco[4];
#pragma unroll
    for (int ct = 0; ct < 4; ct++) acco[ct] = (f32x4){0.f, 0.f, 0.f, 0.f};
#pragma unroll
    for (int kt = 0; kt < 7; kt++) {
      short8 ap = *reinterpret_cast<const short8*>(&Plds[wid][lr][kt * 32 + lk * 8]);
#pragma unroll
      for (int ct = 0; ct < 4; ct++) {
        short8 bv = *reinterpret_cast<const short8*>(&Vt[ct * 16 + lr][kt * 32 + lk * 8]);
        acco[ct] = __builtin_amdgcn_mfma_f32_16x16x32_bf16(ap, bv, acco[ct], 0, 0, 0);
      }
    }
#pragma unroll
    for (int ct = 0; ct < 4; ct++)
#pragma unroll
      for (int j = 0; j < 4; j++) {
        int row = q0 + lk * 4 + j;
        if (row < T_)
          o[(bT + row) * DIM_ + h * HD_ + ct * 16 + lr] = f2b(acco[ct][j]);
      }
  }
}

// ---------------- ToMe matching (fp32, decision-critical) ----------------
__global__ __launch_bounds__(256) void match_kernel(
    const float* __restrict__ metric, const float* __restrict__ asize,
    int* __restrict__ route, float* __restrict__ nsz,
    float* __restrict__ out_ns, float* __restrict__ out_rci) {
  __shared__ float m[197][65];
  __shared__ float nmax[99];
  __shared__ int nidx[99];
  __shared__ int rnk[99];
  __shared__ int srcr[16];
  __shared__ int dstr[16];
  __shared__ int unmp[99];
  int b = blockIdx.x;
  int tid = threadIdx.x;
  int lane = tid & 63, wid = tid >> 6;

  if (tid < T_) {
    const float* mr = metric + ((size_t)b * T_ + tid) * HD_;
    float ss = 0.f;
#pragma unroll
    for (int d = 0; d < 64; d++) { float v = mr[d]; ss = fmaf(v, v, ss); }
    float nrm = sqrtf(ss);
#pragma unroll
    for (int d = 0; d < 64; d++) m[tid][d] = mr[d] / nrm;
  }
  __syncthreads();

  for (int i = wid; i < NE_; i += 4) {
    if (i == 0) {
      if (lane == 0) { nmax[0] = -INFINITY; nidx[0] = 0; }
      continue;
    }
    float bv = -INFINITY;
    int bj = 1 << 30;
    for (int j = lane; j < NO_; j += 64) {
      const float* a = m[2 * i];
      const float* bb = m[2 * j + 1];
      float sdot = 0.f;
#pragma unroll
      for (int d = 0; d < 64; d++) sdot = fmaf(a[d], bb[d], sdot);
      if (sdot > bv) { bv = sdot; bj = j; }
    }
#pragma unroll
    for (int off = 32; off; off >>= 1) {
      float ov = __shfl_down(bv, off, 64);
      int oj = __shfl_down(bj, off, 64);
      if (ov > bv || (ov == bv && oj < bj)) { bv = ov; bj = oj; }
    }
    if (lane == 0) { nmax[i] = bv; nidx[i] = bj; }
  }
  __syncthreads();

  if (tid < NE_) {
    float v = nmax[tid];
    int r = 0;
    for (int i2 = 0; i2 < NE_; i2++) {
      float v2 = nmax[i2];
      r += (v2 > v) || (v2 == v && i2 < tid);
    }
    rnk[tid] = r;
  }
  __syncthreads();
  if (tid < NE_ && rnk[tid] < REFF_) { srcr[rnk[tid]] = tid; dstr[rnk[tid]] = nidx[tid]; }
  __syncthreads();
  if (tid < NE_ && rnk[tid] >= REFF_) {
    int p = 0;
    for (int i2 = 0; i2 < tid; i2++) p += (rnk[i2] >= REFF_);
    unmp[tid] = p;
    int* rr = route + ((size_t)b * TM_ + p) * 18;
    rr[0] = 1;
    rr[1] = 2 * tid;
  }
  if (tid < NO_) {
    int d = tid;
    int* rr = route + ((size_t)b * TM_ + (NE_ - REFF_) + d) * 18;
    int cnt = 1;
    rr[1] = 2 * d + 1;
    for (int r = 0; r < REFF_; r++)
      if (dstr[r] == d) { cnt++; rr[cnt] = 2 * srcr[r]; }
    rr[0] = cnt;
  }
  __syncthreads();

  for (int row = tid; row < TM_; row += 256) {
    const int* rr = route + ((size_t)b * TM_ + row) * 18;
    int cnt = rr[0];
    float s = 0.f;
    for (int t2 = 0; t2 < cnt; t2++) s += asize[(size_t)b * T_ + rr[1 + t2]];
    out_ns[(size_t)b * TM_ + row] = s;
    nsz[(size_t)b * TM_ + row] = s;
  }
  for (int t = 1 + tid; t < T_; t += 256) {
    int val;
    if (t & 1) {
      val = (NE_ - REFF_ - 1) + ((t - 1) >> 1);
    } else {
      int i = t >> 1;
      val = (rnk[i] >= REFF_) ? (unmp[i] - 1) : ((NE_ - REFF_ - 1) + nidx[i]);
    }
    out_rci[(size_t)b * (T_ - 1) + (t - 1)] = (float)val;
  }
}

// ---------------- merged x = merge(x1 * size) / new_size ----------------
__global__ __launch_bounds__(256) void merge_x_kernel(
    const float* __restrict__ x1, const float* __restrict__ asize,
    const int* __restrict__ route, const float* __restrict__ nsz,
    float* __restrict__ xm) {
  int row = blockIdx.x;
  int b = row / TM_;
  const int* rr = route + (size_t)row * 18;
  __shared__ int cnt_s;
  __shared__ int toks[17];
  __shared__ float szs[17];
  int tid = threadIdx.x;
  if (tid == 0) cnt_s = rr[0];
  __syncthreads();
  int cnt = cnt_s;
  if (tid < cnt) {
    int t = rr[1 + tid];
    toks[tid] = t;
    szs[tid] = asize[(size_t)b * T_ + t];
  }
  __syncthreads();
  float ns = nsz[row];
  for (int e = tid; e < DIM_; e += 256) {
    float acc = 0.f;
    for (int c2 = 0; c2 < cnt; c2++)
      acc = fmaf(x1[((size_t)b * T_ + toks[c2]) * DIM_ + e], szs[c2], acc);
    xm[(size_t)row * DIM_ + e] = acc / ns;
  }
}

// ---------------- launch ----------------
extern "C" void kernel_launch(void* const* d_in, const int* in_sizes, int n_in,
                              void* d_out, int out_size, void* d_ws, size_t ws_size,
                              hipStream_t stream) {
  const float* x_in = (const float*)d_in[0];
  const float* asize = (const float*)d_in[1];
  const float* ln1g = (const float*)d_in[2];
  const float* ln1b = (const float*)d_in[3];
  const float* wqkv = (const float*)d_in[4];
  const float* wproj = (const float*)d_in[5];
  const float* bproj = (const float*)d_in[6];
  const float* ln2g = (const float*)d_in[7];
  const float* ln2b = (const float*)d_in[8];
  const float* wfc1 = (const float*)d_in[9];
  const float* bfc1 = (const float*)d_in[10];
  const float* wfc2 = (const float*)d_in[11];
  const float* bfc2 = (const float*)d_in[12];

  char* base = (char*)d_ws;
  float* h    = (float*)(base + BOFF_A);
  ushort* qkvb = (ushort*)(base + BOFF_A);
  float* x1   = (float*)(base + BOFF_A);
  ushort* gbc = (ushort*)(base + BOFF_GBC);
  ushort* hb  = (ushort*)(base + BOFF_B);
  ushort* ob  = (ushort*)(base + BOFF_B);
  float* xm   = (float*)(base + BOFF_C);
  float* met  = (float*)(base + BOFF_D);
  ushort* h2b = (ushort*)(base + BOFF_D);  // overlays met (met dead before LN2)
  float* wkm  = (float*)(base + BOFF_WKM);
  int* route  = (int*)(base + BOFF_RT);
  float* nsz  = (float*)(base + BOFF_NSZ);
  ushort* wqb = (ushort*)(base + BOFF_WQB);
  ushort* wpb = (ushort*)(base + BOFF_WPB);
  ushort* w1b = (ushort*)(base + BOFF_W1B);
  ushort* w2b = (ushort*)(base + BOFF_W2B);

  float* out_x = (float*)d_out;
  float* out_ns = out_x + (size_t)NM_ * DIM_;
  float* out_rci = out_ns + NM_;

  f2b4_kernel<<<(3 * DIM_ * DIM_) / 1024, 256, 0, stream>>>(wqkv, wqb, 3 * DIM_ * DIM_);
  f2b4_kernel<<<(DIM_ * DIM_) / 1024, 256, 0, stream>>>(wproj, wpb, DIM_ * DIM_);
  f2b4_kernel<<<(MLP_ * DIM_) / 1024, 256, 0, stream>>>(wfc1, w1b, MLP_ * DIM_);
  f2b4_kernel<<<(DIM_ * MLP_) / 1024, 256, 0, stream>>>(wfc2, w2b, DIM_ * MLP_);
  wkmean_kernel<<<(HD_ * DIM_ + 255) / 256, 256, 0, stream>>>(wqkv, wkm);

  ln_kernel<<<N_, 256, 0, stream>>>(x_in, ln1g, ln1b, h, hb);
  gemm_bt<<<dim3(1, N_ / 64), 256, 0, stream>>>(h, wkm, met, N_, HD_, DIM_);
  gemm_mfma<<<(3 * DIM_ / 128) * ((N_ + 127) / 128), 256, 0, stream>>>(
      hb, wqb, nullptr, nullptr, nullptr, qkvb, N_, 3 * DIM_, DIM_, 0);
  attn3_kernel<<<B_ * H_, 512, 0, stream>>>(qkvb, asize, ob);
  gemm_mfma<<<(DIM_ / 128) * ((N_ + 127) / 128), 256, 0, stream>>>(
      ob, wpb, bproj, x_in, x1, nullptr, N_, DIM_, DIM_, 0);
  match_kernel<<<B_, 256, 0, stream>>>(met, asize, route, nsz, out_ns, out_rci);
  merge_x_kernel<<<NM_, 256, 0, stream>>>(x1, asize, route, nsz, xm);
  ln_kernel<<<NM_, 256, 0, stream>>>(xm, ln2g, ln2b, nullptr, h2b);

  gemm_mfma<<<(MLP_ / 128) * ((NM_ + 127) / 128), 256, 0, stream>>>(
      h2b, w1b, bfc1, nullptr, nullptr, gbc, NM_, MLP_, DIM_, 1);
  gemm_mfma<<<(DIM_ / 128) * ((NM_ + 127) / 128), 256, 0, stream>>>(
      gbc, w2b, bfc2, xm, out_x, nullptr, NM_, DIM_, MLP_, 0);
}